// Round 7
// baseline (918.311 us; speedup 1.0000x reference)
//
#include <hip/hip_runtime.h>
#include <math.h>

#define RR 4096
#define SS 128
#define PP (RR*SS)
#define TSZ (1u<<19)
#define TMASK (TSZ-1u)

// ---------------- workspace layout ----------------
#define OFF_PART   0                            // 256 doubles
#define OFF_MEAN   2048                         // 1 float
#define OFF_CNT    2304                         // 2 ints
#define OFF_OUT4   4096                         // PP float4 = 8 MB (sd, r, g, b)
#define OFF_TBUF   (OFF_OUT4 + (size_t)PP*16)   // PP float = 2 MB
#define OFF_PLIST  (OFF_TBUF + (size_t)PP*4)    // PP int   = 2 MB
#define OFF_PLIST2 (OFF_PLIST + (size_t)PP*4)   // PP int   = 2 MB
#define OFF_RAYD   (OFF_PLIST2 + (size_t)PP*4)  // RR*8 floats = 128 KB
#define OFF_H1P    (OFF_RAYD + (size_t)RR*32)   // RR*64 floats = 1 MB
#define OFF_GST    (OFF_H1P + (size_t)RR*256)   // PP*16 floats = 33.5 MB worst
#define WS_NEED    (OFF_GST + (size_t)PP*64)
#define OFF_FEAT   (OFF_GST + (size_t)PP*64)    // PP*16 float2 = 67 MB worst
#define WS_NEED2   (OFF_FEAT + (size_t)PP*128)

__device__ const float RESF_G[16] = {
    16.f, 22.f, 30.f, 42.f, 58.f, 80.f, 111.f, 153.f,
    212.f, 294.f, 406.f, 561.f, 775.f, 1072.f, 1481.f, 2047.f};

// ---------------- mean of density grid (deterministic, fp64) ----------------
__global__ void k_mean_part(const float* __restrict__ g, double* __restrict__ part) {
    __shared__ double sm[256];
    int tid = threadIdx.x;
    double s = 0.0;
    for (int i = blockIdx.x * 256 + tid; i < 128 * 128 * 128; i += 256 * 256)
        s += (double)g[i];
    sm[tid] = s;
    __syncthreads();
    for (int off = 128; off > 0; off >>= 1) {
        if (tid < off) sm[tid] += sm[tid + off];
        __syncthreads();
    }
    if (tid == 0) part[blockIdx.x] = sm[0];
}

__global__ void k_mean_fin(const double* __restrict__ part, float* __restrict__ meanf,
                           int* __restrict__ cnt) {
    __shared__ double sm[256];
    int tid = threadIdx.x;
    sm[tid] = part[tid];
    __syncthreads();
    for (int off = 128; off > 0; off >>= 1) {
        if (tid < off) sm[tid] += sm[tid + off];
        __syncthreads();
    }
    if (tid == 0) {
        meanf[0] = (float)(sm[0] / 2097152.0);
        cnt[0] = 0; cnt[1] = 0;
    }
}

// ---------------- per-ray geometry (bitwise-matches reference f32) ----------
__device__ __forceinline__ void ray_geom(
    int r, const int* __restrict__ n, const int* __restrict__ h, const int* __restrict__ w,
    const float* __restrict__ Kall, const float* __restrict__ Eall,
    const float* __restrict__ bds,
    float& d0, float& d1, float& d2, float& ox, float& oy, float& oz,
    float& nearv, float& farv)
{
#pragma clang fp contract(off)
    int ni = n[r];
    const float* K = Kall + ni * 9;
    const float* E = Eall + ni * 16;
    float fx = K[0], cx = K[2], fy = K[4], cy = K[5];
    float wf = (float)w[r], hf = (float)h[r];
    float dc0 = __fdiv_rn(wf + 0.5f - cx, fx);
    float dc1 = __fdiv_rn(hf + 0.5f - cy, fy);
    float dc2 = 1.0f;
    float e0 = E[0] * dc0 + E[1] * dc1 + E[2] * dc2;
    float e1 = E[4] * dc0 + E[5] * dc1 + E[6] * dc2;
    float e2 = E[8] * dc0 + E[9] * dc1 + E[10] * dc2;
    float nn = __fsqrt_rn(e0 * e0 + e1 * e1 + e2 * e2);
    d0 = __fdiv_rn(e0, nn); d1 = __fdiv_rn(e1, nn); d2 = __fdiv_rn(e2, nn);
    ox = E[3]; oy = E[7]; oz = E[11];
    nearv = bds[ni * 2 + 0]; farv = bds[ni * 2 + 1];
}

// per-point t / delta / normalized coords (bitwise-stable, shared by kernels)
__device__ __forceinline__ void point_u(
    int s, int p, const float* __restrict__ rd, const float* __restrict__ tn,
    float& ux, float& uy, float& uz, float& tcur, float& delta)
{
#pragma clang fp contract(off)
    float d0 = rd[0], d1 = rd[1], d2 = rd[2];
    float ox = rd[3], oy = rd[4], oz = rd[5];
    float nearv = rd[6], farv = rd[7];
    float sf = (float)s;
    tcur = nearv + (farv - nearv) * ((sf + tn[p]) / 128.0f);
    if (s < SS - 1) {
        float t2 = nearv + (farv - nearv) * (((sf + 1.0f) + tn[p + 1]) / 128.0f);
        delta = t2 - tcur;
    } else {
        delta = farv - tcur;
    }
    float px = fminf(fmaxf(ox + d0 * tcur, -1.0f), 1.0f);
    float py = fminf(fmaxf(oy + d1 * tcur, -1.0f), 1.0f);
    float pz = fminf(fmaxf(oz + d2 * tcur, -1.0f), 1.0f);
    ux = (px + 1.0f) / 2.0f;
    uy = (py + 1.0f) / 2.0f;
    uz = (pz + 1.0f) / 2.0f;
}

// one hash-grid level; corner order/rounding matches reference exactly
__device__ __forceinline__ void enc_level(
    float ux, float uy, float uz, float res,
    const float* __restrict__ tab, float& f0, float& f1)
{
#pragma clang fp contract(off)
    float px = ux * res, py = uy * res, pz = uz * res;
    float p0x = floorf(px), p0y = floorf(py), p0z = floorf(pz);
    float fxx = px - p0x, fyy = py - p0y, fzz = pz - p0z;
    unsigned x0 = (unsigned)p0x, y0 = (unsigned)p0y, z0 = (unsigned)p0z;
    f0 = 0.f; f1 = 0.f;
    const float2* t2 = (const float2*)tab;
#pragma unroll
    for (int dx = 0; dx < 2; ++dx) {
        unsigned cxi = x0 + (unsigned)dx;
        float wx = dx ? fxx : 1.0f - fxx;
#pragma unroll
        for (int dy = 0; dy < 2; ++dy) {
            unsigned hy = (y0 + (unsigned)dy) * 2654435761u;
            float wy = dy ? fyy : 1.0f - fyy;
#pragma unroll
            for (int dz = 0; dz < 2; ++dz) {
                unsigned hz = (z0 + (unsigned)dz) * 805459861u;
                float wz = dz ? fzz : 1.0f - fzz;
                unsigned hh = (cxi ^ hy ^ hz) & TMASK;
                float2 tv = t2[hh];
                float ww = (wx * wy) * wz;
                f0 = f0 + tv.x * ww;
                f1 = f1 + tv.y * ww;
            }
        }
    }
}

// ---------------- K_ray: per-ray dir/origin/bounds + SH partial of rgb MLP ----
__launch_bounds__(256)
__global__ void k_ray_pre(
    const int* __restrict__ n, const int* __restrict__ h, const int* __restrict__ w,
    const float* __restrict__ intr, const float* __restrict__ extr,
    const float* __restrict__ bds, const float* __restrict__ rw1,
    float* __restrict__ rayd, float* __restrict__ h1p)
{
#pragma clang fp contract(off)
    int wid = threadIdx.x >> 6, lane = threadIdx.x & 63;
    int r = blockIdx.x * 4 + wid;
    float d0, d1, d2, ox, oy, oz, nearv, farv;
    ray_geom(r, n, h, w, intr, extr, bds, d0, d1, d2, ox, oy, oz, nearv, farv);

    float X = d0, Y = d1, Z = d2;
    float xx = X * X, yy = Y * Y, zz = Z * Z;
    float sh[16];
    sh[0] = 0.28209479177387814f;
    sh[1] = -0.48860251190291987f * Y;
    sh[2] = 0.48860251190291987f * Z;
    sh[3] = -0.48860251190291987f * X;
    sh[4] = 1.0925484305920792f * X * Y;
    sh[5] = -1.0925484305920792f * Y * Z;
    sh[6] = 0.94617469575756f * zz - 0.31539156525252005f;
    sh[7] = -1.0925484305920792f * X * Z;
    sh[8] = 0.5462742152960396f * (xx - yy);
    sh[9] = -0.5900435899266435f * Y * (3.0f * xx - yy);
    sh[10] = 2.890611442640554f * X * Y * Z;
    sh[11] = 0.4570457994644657f * Y * (1.0f - 5.0f * zz);
    sh[12] = 0.3731763325901154f * Z * (5.0f * zz - 3.0f);
    sh[13] = 0.4570457994644657f * X * (1.0f - 5.0f * zz);
    sh[14] = 1.445305721320277f * Z * (xx - yy);
    sh[15] = -0.5900435899266435f * X * (xx - 3.0f * yy);

    float acc = 0.f;
#pragma unroll
    for (int k = 0; k < 16; ++k)
        acc = fmaf(sh[k], rw1[k * 64 + lane], acc);
    h1p[r * 64 + lane] = acc;

    if (lane == 0) {
        float* rd = rayd + r * 8;
        rd[0] = d0; rd[1] = d1; rd[2] = d2;
        rd[3] = ox; rd[4] = oy; rd[5] = oz;
        rd[6] = nearv; rd[7] = farv;
    }
}

// ---------------- K_classify: occ test + compaction + defaults ----------------
__launch_bounds__(256)
__global__ void k_classify(
    const float* __restrict__ tn, const float* __restrict__ rayd,
    const float* __restrict__ grid, const float* __restrict__ meanf,
    float* __restrict__ tbuf, float4* __restrict__ out4,
    int* __restrict__ plist, int* __restrict__ cnt)
{
#pragma clang fp contract(off)
    int p = blockIdx.x * 256 + threadIdx.x;
    int r = p >> 7, s = p & 127;
    const float* rd = rayd + r * 8;
    float ux, uy, uz, tcur, delta;
    point_u(s, p, rd, tn, ux, uy, uz, tcur, delta);
    int g0 = min(max((int)(ux * 128.0f), 0), 127);
    int g1 = min(max((int)(uy * 128.0f), 0), 127);
    int g2 = min(max((int)(uz * 128.0f), 0), 127);
    bool occ = grid[(g0 * 128 + g1) * 128 + g2] > meanf[0];

    tbuf[p] = tcur;
    out4[p] = make_float4(0.f, 0.f, 0.f, 0.f);

    unsigned long long m = __ballot(occ);
    int lane = threadIdx.x & 63;
    int nw = __popcll(m);
    int base = 0;
    if (lane == 0 && nw > 0) base = atomicAdd(&cnt[0], nw);
    base = __shfl(base, 0, 64);
    if (occ) {
        int idx = base + __popcll(m & ((1ull << lane) - 1ull));
        plist[idx] = p;
    }
}

// ===== K_enc: one hash level per block.x; XCD-pinned (grid(8,NB), x fastest =>
// linear_bid%8 == blockIdx.x == XCD). Each XCD's level table (4 MB) stays
// resident in its private L2. Two launches cover levels 0-7 and 8-15.
__launch_bounds__(256)
__global__ void k_enc(
    const float* __restrict__ tn, const float* __restrict__ rayd,
    const float* __restrict__ htab,
    const int* __restrict__ plist, const int* __restrict__ cnt,
    float2* __restrict__ feat, int lvl_base)
{
#pragma clang fp contract(off)
    int cnt0 = cnt[0];
    int j0 = blockIdx.y * 256;
    if (j0 >= cnt0) return;
    int l = lvl_base + blockIdx.x;
    int j = j0 + threadIdx.x;
    bool active = j < cnt0;
    int pid = plist[active ? j : 0];
    int r = pid >> 7, s = pid & 127;
    const float* rd = rayd + r * 8;
    float ux, uy, uz, tcur, delta;
    point_u(s, pid, rd, tn, ux, uy, uz, tcur, delta);
    float f0, f1;
    enc_level(ux, uy, uz, RESF_G[l], htab + (size_t)l * (TSZ * 2), f0, f1);
    if (active) feat[(size_t)l * PP + j] = make_float2(f0, f1);
}

// ===== K_sig: M1 (from feats, exact level order) + M2; compaction for rgb ====
__launch_bounds__(256)
__global__ void k_sig(
    const float* __restrict__ tn, const float* __restrict__ rayd,
    const float* __restrict__ sw1, const float* __restrict__ sw2,
    const int* __restrict__ plist, const int* __restrict__ cnt,
    int* __restrict__ cnt2,
    float4* __restrict__ out4, int* __restrict__ plist2, float4* __restrict__ gst4,
    const float2* __restrict__ feat)
{
    __shared__ float L[3328];   // sw1 row-major 32x64 | sw2 64 rows, stride 20
    int tid = threadIdx.x;
    int cnt0 = cnt[0];
    if (blockIdx.x * 256 >= cnt0) return;
    for (int i = tid; i < 2048; i += 256) L[i] = sw1[i];
    for (int i = tid; i < 1088; i += 256) { int rr = i / 17, cc = i - rr * 17; L[2048 + rr * 20 + cc] = sw2[i]; }
    __syncthreads();

    int i = blockIdx.x * 256 + tid;
    bool active = i < cnt0;
    int ii = active ? i : 0;
    int pid = plist[ii];
    int r = pid >> 7, s = pid & 127;

    const float* rd = rayd + r * 8;
    float ux, uy, uz, tcur, delta;
    point_u(s, pid, rd, tn, ux, uy, uz, tcur, delta);

    // ---- M1: features (level order, f0 then f1) -> hh[64]; exact R2 order ----
    float hh[64];
#pragma unroll
    for (int j = 0; j < 64; ++j) hh[j] = 0.f;
#pragma unroll 1
    for (int l = 0; l < 16; ++l) {
        float2 f = feat[(size_t)l * PP + ii];
        const float* w0 = &L[l * 128];
        const float* w1 = w0 + 64;
#pragma unroll
        for (int jq = 0; jq < 16; ++jq) {
            float4 a = *(const float4*)(w0 + jq * 4);
            float4 b = *(const float4*)(w1 + jq * 4);
            hh[jq * 4 + 0] = fmaf(f.y, b.x, fmaf(f.x, a.x, hh[jq * 4 + 0]));
            hh[jq * 4 + 1] = fmaf(f.y, b.y, fmaf(f.x, a.y, hh[jq * 4 + 1]));
            hh[jq * 4 + 2] = fmaf(f.y, b.z, fmaf(f.x, a.z, hh[jq * 4 + 2]));
            hh[jq * 4 + 3] = fmaf(f.y, b.w, fmaf(f.x, a.w, hh[jq * 4 + 3]));
        }
    }

    // ---- M2: relu(h)(64) @ sigma_w2(64x17), k-ascending ----
    float acc[17];
#pragma unroll
    for (int j = 0; j < 17; ++j) acc[j] = 0.f;
#pragma unroll
    for (int k = 0; k < 64; ++k) {
        float hv = fmaxf(hh[k], 0.f);
        const float* wrow = &L[2048 + k * 20];
#pragma unroll
        for (int jq = 0; jq < 4; ++jq) {
            float4 wv = *(const float4*)(wrow + jq * 4);
            acc[jq * 4 + 0] = fmaf(hv, wv.x, acc[jq * 4 + 0]);
            acc[jq * 4 + 1] = fmaf(hv, wv.y, acc[jq * 4 + 1]);
            acc[jq * 4 + 2] = fmaf(hv, wv.z, acc[jq * 4 + 2]);
            acc[jq * 4 + 3] = fmaf(hv, wv.w, acc[jq * 4 + 3]);
        }
        acc[16] = fmaf(hv, wrow[16], acc[16]);
    }

    float sigma = fmaxf(acc[0], 0.f);     // occ known true for active lanes
    float sd = sigma * delta;
    if (active) ((float*)out4)[(size_t)pid * 4] = sd;

    bool pos = active && (sigma > 0.f);
    unsigned long long m = __ballot(pos);
    int lane = tid & 63;
    int nw = __popcll(m);
    int base = 0;
    if (lane == 0 && nw > 0) base = atomicAdd(cnt2, nw);
    base = __shfl(base, 0, 64);
    if (pos) {
        int j2 = base + __popcll(m & ((1ull << lane) - 1ull));
        plist2[j2] = pid;
        gst4[(size_t)j2 * 4 + 0] = make_float4(acc[1], acc[2], acc[3], acc[4]);
        gst4[(size_t)j2 * 4 + 1] = make_float4(acc[5], acc[6], acc[7], acc[8]);
        gst4[(size_t)j2 * 4 + 2] = make_float4(acc[9], acc[10], acc[11], acc[12]);
        gst4[(size_t)j2 * 4 + 3] = make_float4(acc[13], acc[14], acc[15], acc[16]);
    }
}

// ===== K_sigall (round-6 path, used when ws too small for feat buffer) =======
__launch_bounds__(256)
__global__ void k_sigall(
    const float* __restrict__ tn, const float* __restrict__ rayd,
    const float* __restrict__ grid, const float* __restrict__ meanf,
    const float* __restrict__ htab,
    const float* __restrict__ sw1, const float* __restrict__ sw2,
    int* __restrict__ cnt2,
    float4* __restrict__ out4, float* __restrict__ tbuf,
    int* __restrict__ plist2, float4* __restrict__ gst4)
{
    __shared__ float L[5376];
    int tid = threadIdx.x;
    for (int i = tid; i < 2048; i += 256) L[i] = sw1[i];
    for (int i = tid; i < 1088; i += 256) { int rr = i / 17, cc = i - rr * 17; L[2048 + rr * 20 + cc] = sw2[i]; }
    __syncthreads();
    float* buf = L + 3328;

    int p = blockIdx.x * 256 + tid;
    int r = p >> 7, s = p & 127;
    const float* rd = rayd + r * 8;
    float ux, uy, uz, tcur, delta;
    point_u(s, p, rd, tn, ux, uy, uz, tcur, delta);

    int g0 = min(max((int)(ux * 128.0f), 0), 127);
    int g1 = min(max((int)(uy * 128.0f), 0), 127);
    int g2 = min(max((int)(uz * 128.0f), 0), 127);
    bool occ = grid[(g0 * 128 + g1) * 128 + g2] > meanf[0];
    tbuf[p] = tcur;

    float sigma = 0.f;
    float acc[17];
    if (occ) {
        const float RESF[16] = {
            16.f, 22.f, 30.f, 42.f, 58.f, 80.f, 111.f, 153.f,
            212.f, 294.f, 406.f, 561.f, 775.f, 1072.f, 1481.f, 2047.f};

        float hh[64];
#pragma unroll
        for (int j = 0; j < 64; ++j) hh[j] = 0.f;
#pragma unroll 1
        for (int c = 0; c < 4; ++c) {
#pragma unroll
            for (int li = 0; li < 4; ++li) {
                int l = c * 4 + li;
                float f0, f1;
                enc_level(ux, uy, uz, RESF[l], htab + (size_t)l * (TSZ * 2), f0, f1);
                buf[(2 * li) * 256 + tid] = f0;
                buf[(2 * li + 1) * 256 + tid] = f1;
            }
#pragma unroll 1
            for (int k2 = 0; k2 < 8; ++k2) {
                float e = buf[k2 * 256 + tid];
                const float* wrow = &L[(c * 8 + k2) * 64];
#pragma unroll
                for (int jq = 0; jq < 16; ++jq) {
                    float4 wv = *(const float4*)(wrow + jq * 4);
                    hh[jq * 4 + 0] = fmaf(e, wv.x, hh[jq * 4 + 0]);
                    hh[jq * 4 + 1] = fmaf(e, wv.y, hh[jq * 4 + 1]);
                    hh[jq * 4 + 2] = fmaf(e, wv.z, hh[jq * 4 + 2]);
                    hh[jq * 4 + 3] = fmaf(e, wv.w, hh[jq * 4 + 3]);
                }
            }
        }

#pragma unroll
        for (int j = 0; j < 17; ++j) acc[j] = 0.f;
#pragma unroll
        for (int c = 0; c < 8; ++c) {
#pragma unroll
            for (int q = 0; q < 8; ++q) buf[q * 256 + tid] = fmaxf(hh[c * 8 + q], 0.f);
#pragma unroll 1
            for (int k2 = 0; k2 < 8; ++k2) {
                float hv = buf[k2 * 256 + tid];
                const float* wrow = &L[2048 + (c * 8 + k2) * 20];
#pragma unroll
                for (int jq = 0; jq < 4; ++jq) {
                    float4 wv = *(const float4*)(wrow + jq * 4);
                    acc[jq * 4 + 0] = fmaf(hv, wv.x, acc[jq * 4 + 0]);
                    acc[jq * 4 + 1] = fmaf(hv, wv.y, acc[jq * 4 + 1]);
                    acc[jq * 4 + 2] = fmaf(hv, wv.z, acc[jq * 4 + 2]);
                    acc[jq * 4 + 3] = fmaf(hv, wv.w, acc[jq * 4 + 3]);
                }
                acc[16] = fmaf(hv, wrow[16], acc[16]);
            }
        }
        sigma = fmaxf(acc[0], 0.f);
    }

    float sd = occ ? sigma * delta : 0.f;
    out4[p] = make_float4(sd, 0.f, 0.f, 0.f);

    bool pos = occ && (sigma > 0.f);
    unsigned long long m = __ballot(pos);
    int lane = tid & 63;
    int nw = __popcll(m);
    int base = 0;
    if (lane == 0 && nw > 0) base = atomicAdd(cnt2, nw);
    base = __shfl(base, 0, 64);
    if (pos) {
        int j2 = base + __popcll(m & ((1ull << lane) - 1ull));
        plist2[j2] = p;
        gst4[(size_t)j2 * 4 + 0] = make_float4(acc[1], acc[2], acc[3], acc[4]);
        gst4[(size_t)j2 * 4 + 1] = make_float4(acc[5], acc[6], acc[7], acc[8]);
        gst4[(size_t)j2 * 4 + 2] = make_float4(acc[9], acc[10], acc[11], acc[12]);
        gst4[(size_t)j2 * 4 + 3] = make_float4(acc[13], acc[14], acc[15], acc[16]);
    }
}

// ---------------- K_rgb: rgb MLP on sigma>0-compacted points ------------------
__launch_bounds__(256)
__global__ void k_rgb(
    const float* __restrict__ rw1, const float* __restrict__ rw2,
    const float* __restrict__ rw3,
    const int* __restrict__ plist2, const int* __restrict__ cnt2,
    const float* __restrict__ h1p, const float4* __restrict__ gst4,
    float4* __restrict__ out4)
{
    __shared__ float L[7424];
    int tid = threadIdx.x;
    int c2 = cnt2[0];
    if (blockIdx.x * 256 >= c2) return;
    for (int i = tid; i < 1024; i += 256) L[i] = rw1[1024 + i];
    for (int i = tid; i < 4096; i += 256) L[1024 + i] = rw2[i];
    if (tid < 192) { int rr = tid / 3, cc = tid - rr * 3; L[5120 + rr * 4 + cc] = rw3[tid]; }
    __syncthreads();
    float* buf = L + 5376;

    int i = blockIdx.x * 256 + tid;
    bool active = i < c2;
    int ii = active ? i : 0;
    int pid = plist2[ii];
    int r = pid >> 7;

    float hh[64];
    const float4* hp4 = (const float4*)(h1p + (size_t)r * 64);
#pragma unroll
    for (int q = 0; q < 16; ++q) {
        float4 v = hp4[q];
        hh[q * 4 + 0] = v.x; hh[q * 4 + 1] = v.y; hh[q * 4 + 2] = v.z; hh[q * 4 + 3] = v.w;
    }
    float geo[16];
#pragma unroll
    for (int q = 0; q < 4; ++q) {
        float4 g = gst4[(size_t)ii * 4 + q];
        geo[q * 4 + 0] = g.x; geo[q * 4 + 1] = g.y; geo[q * 4 + 2] = g.z; geo[q * 4 + 3] = g.w;
    }

#pragma unroll
    for (int c = 0; c < 2; ++c) {
#pragma unroll
        for (int q = 0; q < 8; ++q) buf[q * 256 + tid] = geo[c * 8 + q];
#pragma unroll 1
        for (int k2 = 0; k2 < 8; ++k2) {
            float xv = buf[k2 * 256 + tid];
            const float* wrow = &L[(c * 8 + k2) * 64];
#pragma unroll
            for (int jq = 0; jq < 16; ++jq) {
                float4 wv = *(const float4*)(wrow + jq * 4);
                hh[jq * 4 + 0] = fmaf(xv, wv.x, hh[jq * 4 + 0]);
                hh[jq * 4 + 1] = fmaf(xv, wv.y, hh[jq * 4 + 1]);
                hh[jq * 4 + 2] = fmaf(xv, wv.z, hh[jq * 4 + 2]);
                hh[jq * 4 + 3] = fmaf(xv, wv.w, hh[jq * 4 + 3]);
            }
        }
    }

    float h2[64];
#pragma unroll
    for (int j = 0; j < 64; ++j) h2[j] = 0.f;
#pragma unroll
    for (int c = 0; c < 8; ++c) {
#pragma unroll
        for (int q = 0; q < 8; ++q) buf[q * 256 + tid] = fmaxf(hh[c * 8 + q], 0.f);
#pragma unroll 1
        for (int k2 = 0; k2 < 8; ++k2) {
            float hv = buf[k2 * 256 + tid];
            const float* wrow = &L[1024 + (c * 8 + k2) * 64];
#pragma unroll
            for (int jq = 0; jq < 16; ++jq) {
                float4 wv = *(const float4*)(wrow + jq * 4);
                h2[jq * 4 + 0] = fmaf(hv, wv.x, h2[jq * 4 + 0]);
                h2[jq * 4 + 1] = fmaf(hv, wv.y, h2[jq * 4 + 1]);
                h2[jq * 4 + 2] = fmaf(hv, wv.z, h2[jq * 4 + 2]);
                h2[jq * 4 + 3] = fmaf(hv, wv.w, h2[jq * 4 + 3]);
            }
        }
    }

    float o0 = 0.f, o1 = 0.f, o2 = 0.f;
#pragma unroll
    for (int k = 0; k < 64; ++k) {
        float hv = fmaxf(h2[k], 0.f);
        float4 wv = *(const float4*)&L[5120 + k * 4];
        o0 = fmaf(hv, wv.x, o0);
        o1 = fmaf(hv, wv.y, o1);
        o2 = fmaf(hv, wv.z, o2);
    }
    float r0 = 1.0f / (1.0f + expf(-o0));
    float r1 = 1.0f / (1.0f + expf(-o1));
    float r2 = 1.0f / (1.0f + expf(-o2));
    if (active) {
        float* o = (float*)&out4[pid];
        o[1] = r0; o[2] = r1; o[3] = r2;
    }
}

// ---------------- compositing: one wave per ray, shfl scan --------------------
__launch_bounds__(256)
__global__ void k_comp(const float4* __restrict__ out4, const float* __restrict__ tb,
                       const float* __restrict__ bg, float* __restrict__ out)
{
#pragma clang fp contract(off)
    int wid = threadIdx.x >> 6, lane = threadIdx.x & 63;
    int r = blockIdx.x * 4 + wid;
    double im0 = 0, im1 = 0, im2 = 0, dep = 0, aw = 0;
    float carry = 0.f;
#pragma unroll
    for (int half = 0; half < 2; ++half) {
        int p = r * 128 + half * 64 + lane;
        float4 v = out4[p];
        float tv = tb[p];
        float sd = v.x;
        float incl = sd;
#pragma unroll
        for (int off = 1; off < 64; off <<= 1) {
            float t = __shfl_up(incl, off, 64);
            if (lane >= off) incl += t;
        }
        float excl = __shfl_up(incl, 1, 64);
        if (lane == 0) excl = 0.f;
        float cum = carry + excl;
        float T = (float)exp(-(double)cum);
        float e1 = (float)exp(-(double)sd);
        float wgt = (1.0f - e1) * T;
        im0 += (double)(wgt * v.y);
        im1 += (double)(wgt * v.z);
        im2 += (double)(wgt * v.w);
        dep += (double)(wgt * tv);
        aw  += (double)wgt;
        carry = carry + __shfl(incl, 63, 64);
    }
#pragma unroll
    for (int off = 32; off > 0; off >>= 1) {
        im0 += __shfl_down(im0, off, 64);
        im1 += __shfl_down(im1, off, 64);
        im2 += __shfl_down(im2, off, 64);
        dep += __shfl_down(dep, off, 64);
        aw  += __shfl_down(aw, off, 64);
    }
    if (lane == 0) {
        float accf = (float)aw;
        out[r * 3 + 0] = (float)im0 + (1.0f - accf) * bg[0];
        out[r * 3 + 1] = (float)im1 + (1.0f - accf) * bg[1];
        out[r * 3 + 2] = (float)im2 + (1.0f - accf) * bg[2];
        out[RR * 3 + r] = (float)dep;
    }
}

// =================== FALLBACK PATH (round-1 kernel, known good) ===============
__device__ __forceinline__ void geom_fb(
    int r, int s,
    const int* __restrict__ n, const int* __restrict__ h, const int* __restrict__ w,
    const float* __restrict__ Kall, const float* __restrict__ Eall,
    const float* __restrict__ bds, const float* __restrict__ tn,
    const float* __restrict__ grid, float meanv,
    float& ux, float& uy, float& uz,
    float& ddx, float& ddy, float& ddz,
    float& tout, float& dlout, bool& occ)
{
#pragma clang fp contract(off)
    int ni = n[r];
    const float* K = Kall + ni * 9;
    const float* E = Eall + ni * 16;
    float fx = K[0], cx = K[2], fy = K[4], cy = K[5];
    float wf = (float)w[r], hf = (float)h[r];
    float dc0 = __fdiv_rn(wf + 0.5f - cx, fx);
    float dc1 = __fdiv_rn(hf + 0.5f - cy, fy);
    float dc2 = 1.0f;
    float d0 = E[0] * dc0 + E[1] * dc1 + E[2] * dc2;
    float d1 = E[4] * dc0 + E[5] * dc1 + E[6] * dc2;
    float d2 = E[8] * dc0 + E[9] * dc1 + E[10] * dc2;
    float nn = __fsqrt_rn(d0 * d0 + d1 * d1 + d2 * d2);
    d0 = __fdiv_rn(d0, nn); d1 = __fdiv_rn(d1, nn); d2 = __fdiv_rn(d2, nn);
    float ox = E[3], oy = E[7], oz = E[11];
    float nearv = bds[ni * 2 + 0], farv = bds[ni * 2 + 1];
    float sf = (float)s;
    float tcur = nearv + (farv - nearv) * ((sf + tn[r * SS + s]) / 128.0f);
    float dl;
    if (s < SS - 1) {
        float t2 = nearv + (farv - nearv) * (((sf + 1.0f) + tn[r * SS + s + 1]) / 128.0f);
        dl = t2 - tcur;
    } else {
        dl = farv - tcur;
    }
    float px = fminf(fmaxf(ox + d0 * tcur, -1.0f), 1.0f);
    float py = fminf(fmaxf(oy + d1 * tcur, -1.0f), 1.0f);
    float pz = fminf(fmaxf(oz + d2 * tcur, -1.0f), 1.0f);
    ux = (px + 1.0f) / 2.0f;
    uy = (py + 1.0f) / 2.0f;
    uz = (pz + 1.0f) / 2.0f;
    int g0 = min(max((int)(ux * 128.0f), 0), 127);
    int g1 = min(max((int)(uy * 128.0f), 0), 127);
    int g2 = min(max((int)(uz * 128.0f), 0), 127);
    occ = grid[(g0 * 128 + g1) * 128 + g2] > meanv;
    ddx = d0; ddy = d1; ddz = d2; tout = tcur; dlout = dl;
}

__launch_bounds__(256)
__global__ void k_points_fb(
    const int* __restrict__ n, const int* __restrict__ h, const int* __restrict__ w,
    const float* __restrict__ intr, const float* __restrict__ extr,
    const float* __restrict__ bds, const float* __restrict__ tn,
    const float* __restrict__ htab,
    const float* __restrict__ sw1, const float* __restrict__ sw2,
    const float* __restrict__ rw1, const float* __restrict__ rw2,
    const float* __restrict__ rw3,
    const float* __restrict__ grid, const float* __restrict__ meanf,
    float4* __restrict__ out4, float* __restrict__ tbuf)
{
    __shared__ float L[9728 + 8 * 256];
    int tid = threadIdx.x;
    for (int i = tid; i < 2048; i += 256) L[i] = sw1[i];
    for (int i = tid; i < 1088; i += 256) { int rr = i / 17, cc = i - rr * 17; L[2048 + rr * 20 + cc] = sw2[i]; }
    for (int i = tid; i < 2048; i += 256) L[3328 + i] = rw1[i];
    for (int i = tid; i < 4096; i += 256) L[5376 + i] = rw2[i];
    if (tid < 192) { int rr = tid / 3, cc = tid - rr * 3; L[9472 + rr * 4 + cc] = rw3[tid]; }
    __syncthreads();
    float* buf = L + 9728;

    int p = blockIdx.x * 256 + tid;
    int r = p >> 7, s = p & 127;
    float ux, uy, uz, d0, d1, d2, tcur, delta;
    bool occ;
    geom_fb(r, s, n, h, w, intr, extr, bds, tn, grid, meanf[0],
            ux, uy, uz, d0, d1, d2, tcur, delta, occ);

    float hh[64];
#pragma unroll
    for (int j = 0; j < 64; ++j) hh[j] = 0.f;
#pragma unroll 1
    for (int c = 0; c < 4; ++c) {
#pragma unroll 1
        for (int li = 0; li < 4; ++li) {
            int l = c * 4 + li;
            float f0, f1;
            enc_level(ux, uy, uz, RESF_G[l], htab + (size_t)l * (TSZ * 2), f0, f1);
            buf[(2 * li) * 256 + tid] = f0;
            buf[(2 * li + 1) * 256 + tid] = f1;
        }
#pragma unroll 1
        for (int k2 = 0; k2 < 8; ++k2) {
            float e = buf[k2 * 256 + tid];
            const float* wrow = &L[(c * 8 + k2) * 64];
#pragma unroll
            for (int jq = 0; jq < 16; ++jq) {
                float4 wv = *(const float4*)(wrow + jq * 4);
                hh[jq * 4 + 0] = fmaf(e, wv.x, hh[jq * 4 + 0]);
                hh[jq * 4 + 1] = fmaf(e, wv.y, hh[jq * 4 + 1]);
                hh[jq * 4 + 2] = fmaf(e, wv.z, hh[jq * 4 + 2]);
                hh[jq * 4 + 3] = fmaf(e, wv.w, hh[jq * 4 + 3]);
            }
        }
    }
    float acc[17];
#pragma unroll
    for (int j = 0; j < 17; ++j) acc[j] = 0.f;
#pragma unroll
    for (int c = 0; c < 8; ++c) {
#pragma unroll
        for (int q = 0; q < 8; ++q) buf[q * 256 + tid] = fmaxf(hh[c * 8 + q], 0.f);
#pragma unroll 1
        for (int k2 = 0; k2 < 8; ++k2) {
            float hv = buf[k2 * 256 + tid];
            const float* wrow = &L[2048 + (c * 8 + k2) * 20];
#pragma unroll
            for (int jq = 0; jq < 4; ++jq) {
                float4 wv = *(const float4*)(wrow + jq * 4);
                acc[jq * 4 + 0] = fmaf(hv, wv.x, acc[jq * 4 + 0]);
                acc[jq * 4 + 1] = fmaf(hv, wv.y, acc[jq * 4 + 1]);
                acc[jq * 4 + 2] = fmaf(hv, wv.z, acc[jq * 4 + 2]);
                acc[jq * 4 + 3] = fmaf(hv, wv.w, acc[jq * 4 + 3]);
            }
            acc[16] = fmaf(hv, wrow[16], acc[16]);
        }
    }
    float sigma = occ ? fmaxf(acc[0], 0.f) : 0.f;

    float X = d0, Y = d1, Z = d2;
    float xx = X * X, yy = Y * Y, zz = Z * Z;
    float sh[16];
    sh[0] = 0.28209479177387814f;
    sh[1] = -0.48860251190291987f * Y;
    sh[2] = 0.48860251190291987f * Z;
    sh[3] = -0.48860251190291987f * X;
    sh[4] = 1.0925484305920792f * X * Y;
    sh[5] = -1.0925484305920792f * Y * Z;
    sh[6] = 0.94617469575756f * zz - 0.31539156525252005f;
    sh[7] = -1.0925484305920792f * X * Z;
    sh[8] = 0.5462742152960396f * (xx - yy);
    sh[9] = -0.5900435899266435f * Y * (3.0f * xx - yy);
    sh[10] = 2.890611442640554f * X * Y * Z;
    sh[11] = 0.4570457994644657f * Y * (1.0f - 5.0f * zz);
    sh[12] = 0.3731763325901154f * Z * (5.0f * zz - 3.0f);
    sh[13] = 0.4570457994644657f * X * (1.0f - 5.0f * zz);
    sh[14] = 1.445305721320277f * Z * (xx - yy);
    sh[15] = -0.5900435899266435f * X * (xx - 3.0f * yy);

#pragma unroll
    for (int j = 0; j < 64; ++j) hh[j] = 0.f;
#pragma unroll
    for (int c = 0; c < 4; ++c) {
#pragma unroll
        for (int q = 0; q < 8; ++q) {
            int k = c * 8 + q;
            float xv = (k < 16) ? sh[k & 15] : acc[1 + (k - 16)];
            buf[q * 256 + tid] = xv;
        }
#pragma unroll 1
        for (int k2 = 0; k2 < 8; ++k2) {
            float xv = buf[k2 * 256 + tid];
            const float* wrow = &L[3328 + (c * 8 + k2) * 64];
#pragma unroll
            for (int jq = 0; jq < 16; ++jq) {
                float4 wv = *(const float4*)(wrow + jq * 4);
                hh[jq * 4 + 0] = fmaf(xv, wv.x, hh[jq * 4 + 0]);
                hh[jq * 4 + 1] = fmaf(xv, wv.y, hh[jq * 4 + 1]);
                hh[jq * 4 + 2] = fmaf(xv, wv.z, hh[jq * 4 + 2]);
                hh[jq * 4 + 3] = fmaf(xv, wv.w, hh[jq * 4 + 3]);
            }
        }
    }
    float h2[64];
#pragma unroll
    for (int j = 0; j < 64; ++j) h2[j] = 0.f;
#pragma unroll
    for (int c = 0; c < 8; ++c) {
#pragma unroll
        for (int q = 0; q < 8; ++q) buf[q * 256 + tid] = fmaxf(hh[c * 8 + q], 0.f);
#pragma unroll 1
        for (int k2 = 0; k2 < 8; ++k2) {
            float hv = buf[k2 * 256 + tid];
            const float* wrow = &L[5376 + (c * 8 + k2) * 64];
#pragma unroll
            for (int jq = 0; jq < 16; ++jq) {
                float4 wv = *(const float4*)(wrow + jq * 4);
                h2[jq * 4 + 0] = fmaf(hv, wv.x, h2[jq * 4 + 0]);
                h2[jq * 4 + 1] = fmaf(hv, wv.y, h2[jq * 4 + 1]);
                h2[jq * 4 + 2] = fmaf(hv, wv.z, h2[jq * 4 + 2]);
                h2[jq * 4 + 3] = fmaf(hv, wv.w, h2[jq * 4 + 3]);
            }
        }
    }
    float o0 = 0.f, o1 = 0.f, o2 = 0.f;
#pragma unroll
    for (int k = 0; k < 64; ++k) {
        float hv = fmaxf(h2[k], 0.f);
        float4 wv = *(const float4*)&L[9472 + k * 4];
        o0 = fmaf(hv, wv.x, o0);
        o1 = fmaf(hv, wv.y, o1);
        o2 = fmaf(hv, wv.z, o2);
    }
    float r0 = 1.0f / (1.0f + expf(-o0));
    float r1 = 1.0f / (1.0f + expf(-o1));
    float r2 = 1.0f / (1.0f + expf(-o2));

    float4 ov;
    ov.x = sigma * delta;
    ov.y = r0; ov.z = r1; ov.w = r2;
    out4[p] = ov;
    tbuf[p] = tcur;
}

__global__ void k_rays_fb(const float4* __restrict__ pt4, const float* __restrict__ tb,
                          const float* __restrict__ bg, float* __restrict__ out)
{
    int r = blockIdx.x * blockDim.x + threadIdx.x;
    if (r >= RR) return;
    float cum = 0.f;
    double im0 = 0, im1 = 0, im2 = 0, dep = 0, aw = 0;
    for (int s = 0; s < SS; ++s) {
        float4 v = pt4[r * SS + s];
        float tv = tb[r * SS + s];
        float T = (float)exp(-(double)cum);
        float e = (float)exp(-(double)v.x);
        float wgt = (1.0f - e) * T;
        im0 += (double)(wgt * v.y);
        im1 += (double)(wgt * v.z);
        im2 += (double)(wgt * v.w);
        dep += (double)(wgt * tv);
        aw  += (double)wgt;
        cum += v.x;
    }
    float accf = (float)aw;
    out[r * 3 + 0] = (float)im0 + (1.0f - accf) * bg[0];
    out[r * 3 + 1] = (float)im1 + (1.0f - accf) * bg[1];
    out[r * 3 + 2] = (float)im2 + (1.0f - accf) * bg[2];
    out[RR * 3 + r] = (float)dep;
}

// ============================ launch =========================================
extern "C" void kernel_launch(void* const* d_in, const int* in_sizes, int n_in,
                              void* d_out, int out_size, void* d_ws, size_t ws_size,
                              hipStream_t stream) {
    const int*   n    = (const int*)d_in[0];
    const int*   h    = (const int*)d_in[1];
    const int*   w    = (const int*)d_in[2];
    const float* intr = (const float*)d_in[3];
    const float* extr = (const float*)d_in[4];
    const float* bds  = (const float*)d_in[5];
    const float* tn   = (const float*)d_in[6];
    const float* htab = (const float*)d_in[7];
    const float* sw1  = (const float*)d_in[8];
    const float* sw2  = (const float*)d_in[9];
    const float* rw1  = (const float*)d_in[10];
    const float* rw2  = (const float*)d_in[11];
    const float* rw3  = (const float*)d_in[12];
    const float* grid = (const float*)d_in[13];
    const float* bg   = (const float*)d_in[14];

    char* ws = (char*)d_ws;
    double* part   = (double*)(ws + OFF_PART);
    float*  meanf  = (float*)(ws + OFF_MEAN);
    int*    cnt    = (int*)(ws + OFF_CNT);
    float4* out4   = (float4*)(ws + OFF_OUT4);
    float*  tbuf   = (float*)(ws + OFF_TBUF);
    int*    plist  = (int*)(ws + OFF_PLIST);
    int*    plist2 = (int*)(ws + OFF_PLIST2);
    float*  rayd   = (float*)(ws + OFF_RAYD);
    float*  h1p    = (float*)(ws + OFF_H1P);
    float4* gst4   = (float4*)(ws + OFF_GST);
    float2* feat   = (float2*)(ws + OFF_FEAT);
    float*  out    = (float*)d_out;

    k_mean_part<<<dim3(256), dim3(256), 0, stream>>>(grid, part);
    k_mean_fin<<<dim3(1), dim3(256), 0, stream>>>(part, meanf, cnt);

    if (ws_size >= WS_NEED2) {
        // XCD level-pinned split-encode path
        k_ray_pre<<<dim3(RR / 4), dim3(256), 0, stream>>>(
            n, h, w, intr, extr, bds, rw1, rayd, h1p);
        k_classify<<<dim3(PP / 256), dim3(256), 0, stream>>>(
            tn, rayd, grid, meanf, tbuf, out4, plist, cnt);
        k_enc<<<dim3(8, PP / 256), dim3(256), 0, stream>>>(
            tn, rayd, htab, plist, cnt, feat, 0);
        k_enc<<<dim3(8, PP / 256), dim3(256), 0, stream>>>(
            tn, rayd, htab, plist, cnt, feat, 8);
        k_sig<<<dim3(PP / 256), dim3(256), 0, stream>>>(
            tn, rayd, sw1, sw2, plist, cnt, cnt + 1, out4, plist2, gst4, feat);
        k_rgb<<<dim3(PP / 256), dim3(256), 0, stream>>>(
            rw1, rw2, rw3, plist2, cnt + 1, h1p, gst4, out4);
        k_comp<<<dim3(RR / 4), dim3(256), 0, stream>>>(out4, tbuf, bg, out);
    } else if (ws_size >= WS_NEED) {
        // round-6 fused path
        k_ray_pre<<<dim3(RR / 4), dim3(256), 0, stream>>>(
            n, h, w, intr, extr, bds, rw1, rayd, h1p);
        k_sigall<<<dim3(PP / 256), dim3(256), 0, stream>>>(
            tn, rayd, grid, meanf, htab, sw1, sw2, cnt + 1, out4, tbuf, plist2, gst4);
        k_rgb<<<dim3(PP / 256), dim3(256), 0, stream>>>(
            rw1, rw2, rw3, plist2, cnt + 1, h1p, gst4, out4);
        k_comp<<<dim3(RR / 4), dim3(256), 0, stream>>>(out4, tbuf, bg, out);
    } else {
        k_points_fb<<<dim3(PP / 256), dim3(256), 0, stream>>>(
            n, h, w, intr, extr, bds, tn, htab, sw1, sw2, rw1, rw2, rw3,
            grid, meanf, out4, tbuf);
        k_rays_fb<<<dim3((RR + 255) / 256), dim3(256), 0, stream>>>(out4, tbuf, bg, out);
    }
}

// Round 8
// 377.962 us; speedup vs baseline: 2.4296x; 2.4296x over previous
//
#include <hip/hip_runtime.h>
#include <math.h>

#define RR 4096
#define SS 128
#define PP (RR*SS)
#define TSZ (1u<<19)
#define TMASK (TSZ-1u)

// ---------------- workspace layout ----------------
#define OFF_PART   0                            // 256 doubles
#define OFF_MEAN   2048                         // 1 float
#define OFF_CNT    2304                         // 2 ints
#define OFF_OUT4   4096                         // PP float4 = 8 MB (sd, r, g, b)
#define OFF_TBUF   (OFF_OUT4 + (size_t)PP*16)   // PP float = 2 MB
#define OFF_PLIST  (OFF_TBUF + (size_t)PP*4)    // PP int   = 2 MB
#define OFF_PLIST2 (OFF_PLIST + (size_t)PP*4)   // PP int   = 2 MB
#define OFF_RAYD   (OFF_PLIST2 + (size_t)PP*4)  // RR*8 floats = 128 KB
#define OFF_H1P    (OFF_RAYD + (size_t)RR*32)   // RR*64 floats = 1 MB
#define OFF_GST    (OFF_H1P + (size_t)RR*256)   // PP*16 floats = 33.5 MB worst
#define WS_NEED    (OFF_GST + (size_t)PP*64)
#define OFF_FEAT   (OFF_GST + (size_t)PP*64)    // PP*16 float2 = 67 MB worst
#define WS_NEED2   (OFF_FEAT + (size_t)PP*128)

__device__ const float RESF_G[16] = {
    16.f, 22.f, 30.f, 42.f, 58.f, 80.f, 111.f, 153.f,
    212.f, 294.f, 406.f, 561.f, 775.f, 1072.f, 1481.f, 2047.f};

// ---------------- mean of density grid (deterministic, fp64) ----------------
__global__ void k_mean_part(const float* __restrict__ g, double* __restrict__ part) {
    __shared__ double sm[256];
    int tid = threadIdx.x;
    double s = 0.0;
    for (int i = blockIdx.x * 256 + tid; i < 128 * 128 * 128; i += 256 * 256)
        s += (double)g[i];
    sm[tid] = s;
    __syncthreads();
    for (int off = 128; off > 0; off >>= 1) {
        if (tid < off) sm[tid] += sm[tid + off];
        __syncthreads();
    }
    if (tid == 0) part[blockIdx.x] = sm[0];
}

__global__ void k_mean_fin(const double* __restrict__ part, float* __restrict__ meanf,
                           int* __restrict__ cnt) {
    __shared__ double sm[256];
    int tid = threadIdx.x;
    sm[tid] = part[tid];
    __syncthreads();
    for (int off = 128; off > 0; off >>= 1) {
        if (tid < off) sm[tid] += sm[tid + off];
        __syncthreads();
    }
    if (tid == 0) {
        meanf[0] = (float)(sm[0] / 2097152.0);
        cnt[0] = 0; cnt[1] = 0;
    }
}

// ---------------- per-ray geometry (bitwise-matches reference f32) ----------
__device__ __forceinline__ void ray_geom(
    int r, const int* __restrict__ n, const int* __restrict__ h, const int* __restrict__ w,
    const float* __restrict__ Kall, const float* __restrict__ Eall,
    const float* __restrict__ bds,
    float& d0, float& d1, float& d2, float& ox, float& oy, float& oz,
    float& nearv, float& farv)
{
#pragma clang fp contract(off)
    int ni = n[r];
    const float* K = Kall + ni * 9;
    const float* E = Eall + ni * 16;
    float fx = K[0], cx = K[2], fy = K[4], cy = K[5];
    float wf = (float)w[r], hf = (float)h[r];
    float dc0 = __fdiv_rn(wf + 0.5f - cx, fx);
    float dc1 = __fdiv_rn(hf + 0.5f - cy, fy);
    float dc2 = 1.0f;
    float e0 = E[0] * dc0 + E[1] * dc1 + E[2] * dc2;
    float e1 = E[4] * dc0 + E[5] * dc1 + E[6] * dc2;
    float e2 = E[8] * dc0 + E[9] * dc1 + E[10] * dc2;
    float nn = __fsqrt_rn(e0 * e0 + e1 * e1 + e2 * e2);
    d0 = __fdiv_rn(e0, nn); d1 = __fdiv_rn(e1, nn); d2 = __fdiv_rn(e2, nn);
    ox = E[3]; oy = E[7]; oz = E[11];
    nearv = bds[ni * 2 + 0]; farv = bds[ni * 2 + 1];
}

// per-point t / delta / normalized coords (bitwise-stable, shared by kernels)
__device__ __forceinline__ void point_u(
    int s, int p, const float* __restrict__ rd, const float* __restrict__ tn,
    float& ux, float& uy, float& uz, float& tcur, float& delta)
{
#pragma clang fp contract(off)
    float d0 = rd[0], d1 = rd[1], d2 = rd[2];
    float ox = rd[3], oy = rd[4], oz = rd[5];
    float nearv = rd[6], farv = rd[7];
    float sf = (float)s;
    tcur = nearv + (farv - nearv) * ((sf + tn[p]) / 128.0f);
    if (s < SS - 1) {
        float t2 = nearv + (farv - nearv) * (((sf + 1.0f) + tn[p + 1]) / 128.0f);
        delta = t2 - tcur;
    } else {
        delta = farv - tcur;
    }
    float px = fminf(fmaxf(ox + d0 * tcur, -1.0f), 1.0f);
    float py = fminf(fmaxf(oy + d1 * tcur, -1.0f), 1.0f);
    float pz = fminf(fmaxf(oz + d2 * tcur, -1.0f), 1.0f);
    ux = (px + 1.0f) / 2.0f;
    uy = (py + 1.0f) / 2.0f;
    uz = (pz + 1.0f) / 2.0f;
}

// one hash-grid level; corner order/rounding matches reference exactly
__device__ __forceinline__ void enc_level(
    float ux, float uy, float uz, float res,
    const float* __restrict__ tab, float& f0, float& f1)
{
#pragma clang fp contract(off)
    float px = ux * res, py = uy * res, pz = uz * res;
    float p0x = floorf(px), p0y = floorf(py), p0z = floorf(pz);
    float fxx = px - p0x, fyy = py - p0y, fzz = pz - p0z;
    unsigned x0 = (unsigned)p0x, y0 = (unsigned)p0y, z0 = (unsigned)p0z;
    f0 = 0.f; f1 = 0.f;
    const float2* t2 = (const float2*)tab;
#pragma unroll
    for (int dx = 0; dx < 2; ++dx) {
        unsigned cxi = x0 + (unsigned)dx;
        float wx = dx ? fxx : 1.0f - fxx;
#pragma unroll
        for (int dy = 0; dy < 2; ++dy) {
            unsigned hy = (y0 + (unsigned)dy) * 2654435761u;
            float wy = dy ? fyy : 1.0f - fyy;
#pragma unroll
            for (int dz = 0; dz < 2; ++dz) {
                unsigned hz = (z0 + (unsigned)dz) * 805459861u;
                float wz = dz ? fzz : 1.0f - fzz;
                unsigned hh = (cxi ^ hy ^ hz) & TMASK;
                float2 tv = t2[hh];
                float ww = (wx * wy) * wz;
                f0 = f0 + tv.x * ww;
                f1 = f1 + tv.y * ww;
            }
        }
    }
}

// ---------------- K_ray: per-ray dir/origin/bounds + SH partial of rgb MLP ----
__launch_bounds__(256)
__global__ void k_ray_pre(
    const int* __restrict__ n, const int* __restrict__ h, const int* __restrict__ w,
    const float* __restrict__ intr, const float* __restrict__ extr,
    const float* __restrict__ bds, const float* __restrict__ rw1,
    float* __restrict__ rayd, float* __restrict__ h1p)
{
#pragma clang fp contract(off)
    int wid = threadIdx.x >> 6, lane = threadIdx.x & 63;
    int r = blockIdx.x * 4 + wid;
    float d0, d1, d2, ox, oy, oz, nearv, farv;
    ray_geom(r, n, h, w, intr, extr, bds, d0, d1, d2, ox, oy, oz, nearv, farv);

    float X = d0, Y = d1, Z = d2;
    float xx = X * X, yy = Y * Y, zz = Z * Z;
    float sh[16];
    sh[0] = 0.28209479177387814f;
    sh[1] = -0.48860251190291987f * Y;
    sh[2] = 0.48860251190291987f * Z;
    sh[3] = -0.48860251190291987f * X;
    sh[4] = 1.0925484305920792f * X * Y;
    sh[5] = -1.0925484305920792f * Y * Z;
    sh[6] = 0.94617469575756f * zz - 0.31539156525252005f;
    sh[7] = -1.0925484305920792f * X * Z;
    sh[8] = 0.5462742152960396f * (xx - yy);
    sh[9] = -0.5900435899266435f * Y * (3.0f * xx - yy);
    sh[10] = 2.890611442640554f * X * Y * Z;
    sh[11] = 0.4570457994644657f * Y * (1.0f - 5.0f * zz);
    sh[12] = 0.3731763325901154f * Z * (5.0f * zz - 3.0f);
    sh[13] = 0.4570457994644657f * X * (1.0f - 5.0f * zz);
    sh[14] = 1.445305721320277f * Z * (xx - yy);
    sh[15] = -0.5900435899266435f * X * (xx - 3.0f * yy);

    float acc = 0.f;
#pragma unroll
    for (int k = 0; k < 16; ++k)
        acc = fmaf(sh[k], rw1[k * 64 + lane], acc);
    h1p[r * 64 + lane] = acc;

    if (lane == 0) {
        float* rd = rayd + r * 8;
        rd[0] = d0; rd[1] = d1; rd[2] = d2;
        rd[3] = ox; rd[4] = oy; rd[5] = oz;
        rd[6] = nearv; rd[7] = farv;
    }
}

// ---------------- K_classify: occ test + compaction + defaults ----------------
__launch_bounds__(256)
__global__ void k_classify(
    const float* __restrict__ tn, const float* __restrict__ rayd,
    const float* __restrict__ grid, const float* __restrict__ meanf,
    float* __restrict__ tbuf, float4* __restrict__ out4,
    int* __restrict__ plist, int* __restrict__ cnt)
{
#pragma clang fp contract(off)
    int p = blockIdx.x * 256 + threadIdx.x;
    int r = p >> 7, s = p & 127;
    const float* rd = rayd + r * 8;
    float ux, uy, uz, tcur, delta;
    point_u(s, p, rd, tn, ux, uy, uz, tcur, delta);
    int g0 = min(max((int)(ux * 128.0f), 0), 127);
    int g1 = min(max((int)(uy * 128.0f), 0), 127);
    int g2 = min(max((int)(uz * 128.0f), 0), 127);
    bool occ = grid[(g0 * 128 + g1) * 128 + g2] > meanf[0];

    tbuf[p] = tcur;
    out4[p] = make_float4(0.f, 0.f, 0.f, 0.f);

    unsigned long long m = __ballot(occ);
    int lane = threadIdx.x & 63;
    int nw = __popcll(m);
    int base = 0;
    if (lane == 0 && nw > 0) base = atomicAdd(&cnt[0], nw);
    base = __shfl(base, 0, 64);
    if (occ) {
        int idx = base + __popcll(m & ((1ull << lane) - 1ull));
        plist[idx] = p;
    }
}

// ===== K_enc: one hash level per block.x; XCD-pinned (grid(8,NB), x fastest =>
// linear_bid%8 == blockIdx.x == XCD). Each XCD's level table (4 MB) stays
// resident in its private L2. Two launches cover levels 0-7 and 8-15.
__launch_bounds__(256)
__global__ void k_enc(
    const float* __restrict__ tn, const float* __restrict__ rayd,
    const float* __restrict__ htab,
    const int* __restrict__ plist, const int* __restrict__ cnt,
    float2* __restrict__ feat, int lvl_base)
{
#pragma clang fp contract(off)
    int cnt0 = cnt[0];
    int j0 = blockIdx.y * 256;
    if (j0 >= cnt0) return;
    int l = lvl_base + blockIdx.x;
    int j = j0 + threadIdx.x;
    bool active = j < cnt0;
    int pid = plist[active ? j : 0];
    int r = pid >> 7, s = pid & 127;
    const float* rd = rayd + r * 8;
    float ux, uy, uz, tcur, delta;
    point_u(s, pid, rd, tn, ux, uy, uz, tcur, delta);
    float f0, f1;
    enc_level(ux, uy, uz, RESF_G[l], htab + (size_t)l * (TSZ * 2), f0, f1);
    if (active) feat[(size_t)l * PP + j] = make_float2(f0, f1);
}

// ===== K_sig: R2-proven register shape; features from feat buffer ===========
// M1/M2 bodies are copied verbatim from the round-2 k_sigma (60 VGPR, no
// scratch): features staged through the LDS buf, one scalar e per weight row,
// chunked M2 with relu round-trip. Only the feature SOURCE differs (coalesced
// feat load instead of enc_level gathers). Bit-identical arithmetic.
__launch_bounds__(256)
__global__ void k_sig(
    const float* __restrict__ tn, const float* __restrict__ rayd,
    const float* __restrict__ sw1, const float* __restrict__ sw2,
    const int* __restrict__ plist, const int* __restrict__ cnt,
    int* __restrict__ cnt2,
    float4* __restrict__ out4, int* __restrict__ plist2, float4* __restrict__ gst4,
    const float2* __restrict__ feat)
{
    __shared__ float L[5376];   // sw1 32x64 | sw2 64 rows stride 20 | buf 8x256
    int tid = threadIdx.x;
    int cnt0 = cnt[0];
    if (blockIdx.x * 256 >= cnt0) return;
    for (int i = tid; i < 2048; i += 256) L[i] = sw1[i];
    for (int i = tid; i < 1088; i += 256) { int rr = i / 17, cc = i - rr * 17; L[2048 + rr * 20 + cc] = sw2[i]; }
    __syncthreads();
    float* buf = L + 3328;

    int i = blockIdx.x * 256 + tid;
    bool active = i < cnt0;
    int ii = active ? i : 0;
    int pid = plist[ii];
    int r = pid >> 7, s = pid & 127;

    const float* rd = rayd + r * 8;
    float ux, uy, uz, tcur, delta;
    point_u(s, pid, rd, tn, ux, uy, uz, tcur, delta);

    // ---- M1: feat (level order) -> LDS buf -> hh[64]; exact R2 structure ----
    float hh[64];
#pragma unroll
    for (int j = 0; j < 64; ++j) hh[j] = 0.f;
#pragma unroll 1
    for (int c = 0; c < 4; ++c) {
#pragma unroll
        for (int li = 0; li < 4; ++li) {
            float2 f = feat[(size_t)(c * 4 + li) * PP + ii];
            buf[(2 * li) * 256 + tid] = f.x;
            buf[(2 * li + 1) * 256 + tid] = f.y;
        }
#pragma unroll 1
        for (int k2 = 0; k2 < 8; ++k2) {
            float e = buf[k2 * 256 + tid];
            const float* wrow = &L[(c * 8 + k2) * 64];
#pragma unroll
            for (int jq = 0; jq < 16; ++jq) {
                float4 wv = *(const float4*)(wrow + jq * 4);
                hh[jq * 4 + 0] = fmaf(e, wv.x, hh[jq * 4 + 0]);
                hh[jq * 4 + 1] = fmaf(e, wv.y, hh[jq * 4 + 1]);
                hh[jq * 4 + 2] = fmaf(e, wv.z, hh[jq * 4 + 2]);
                hh[jq * 4 + 3] = fmaf(e, wv.w, hh[jq * 4 + 3]);
            }
        }
    }

    // ---- M2: relu(h)(64) @ sigma_w2(64x17); exact R2 structure ----
    float acc[17];
#pragma unroll
    for (int j = 0; j < 17; ++j) acc[j] = 0.f;
#pragma unroll
    for (int c = 0; c < 8; ++c) {
#pragma unroll
        for (int q = 0; q < 8; ++q) buf[q * 256 + tid] = fmaxf(hh[c * 8 + q], 0.f);
#pragma unroll 1
        for (int k2 = 0; k2 < 8; ++k2) {
            float hv = buf[k2 * 256 + tid];
            const float* wrow = &L[2048 + (c * 8 + k2) * 20];
#pragma unroll
            for (int jq = 0; jq < 4; ++jq) {
                float4 wv = *(const float4*)(wrow + jq * 4);
                acc[jq * 4 + 0] = fmaf(hv, wv.x, acc[jq * 4 + 0]);
                acc[jq * 4 + 1] = fmaf(hv, wv.y, acc[jq * 4 + 1]);
                acc[jq * 4 + 2] = fmaf(hv, wv.z, acc[jq * 4 + 2]);
                acc[jq * 4 + 3] = fmaf(hv, wv.w, acc[jq * 4 + 3]);
            }
            acc[16] = fmaf(hv, wrow[16], acc[16]);
        }
    }

    float sigma = fmaxf(acc[0], 0.f);     // occ known true for active lanes
    float sd = sigma * delta;
    if (active) ((float*)out4)[(size_t)pid * 4] = sd;

    bool pos = active && (sigma > 0.f);
    unsigned long long m = __ballot(pos);
    int lane = tid & 63;
    int nw = __popcll(m);
    int base = 0;
    if (lane == 0 && nw > 0) base = atomicAdd(cnt2, nw);
    base = __shfl(base, 0, 64);
    if (pos) {
        int j2 = base + __popcll(m & ((1ull << lane) - 1ull));
        plist2[j2] = pid;
        gst4[(size_t)j2 * 4 + 0] = make_float4(acc[1], acc[2], acc[3], acc[4]);
        gst4[(size_t)j2 * 4 + 1] = make_float4(acc[5], acc[6], acc[7], acc[8]);
        gst4[(size_t)j2 * 4 + 2] = make_float4(acc[9], acc[10], acc[11], acc[12]);
        gst4[(size_t)j2 * 4 + 3] = make_float4(acc[13], acc[14], acc[15], acc[16]);
    }
}

// ===== K_sigall (round-6 path, used when ws too small for feat buffer) =======
__launch_bounds__(256)
__global__ void k_sigall(
    const float* __restrict__ tn, const float* __restrict__ rayd,
    const float* __restrict__ grid, const float* __restrict__ meanf,
    const float* __restrict__ htab,
    const float* __restrict__ sw1, const float* __restrict__ sw2,
    int* __restrict__ cnt2,
    float4* __restrict__ out4, float* __restrict__ tbuf,
    int* __restrict__ plist2, float4* __restrict__ gst4)
{
    __shared__ float L[5376];
    int tid = threadIdx.x;
    for (int i = tid; i < 2048; i += 256) L[i] = sw1[i];
    for (int i = tid; i < 1088; i += 256) { int rr = i / 17, cc = i - rr * 17; L[2048 + rr * 20 + cc] = sw2[i]; }
    __syncthreads();
    float* buf = L + 3328;

    int p = blockIdx.x * 256 + tid;
    int r = p >> 7, s = p & 127;
    const float* rd = rayd + r * 8;
    float ux, uy, uz, tcur, delta;
    point_u(s, p, rd, tn, ux, uy, uz, tcur, delta);

    int g0 = min(max((int)(ux * 128.0f), 0), 127);
    int g1 = min(max((int)(uy * 128.0f), 0), 127);
    int g2 = min(max((int)(uz * 128.0f), 0), 127);
    bool occ = grid[(g0 * 128 + g1) * 128 + g2] > meanf[0];
    tbuf[p] = tcur;

    float sigma = 0.f;
    float acc[17];
    if (occ) {
        const float RESF[16] = {
            16.f, 22.f, 30.f, 42.f, 58.f, 80.f, 111.f, 153.f,
            212.f, 294.f, 406.f, 561.f, 775.f, 1072.f, 1481.f, 2047.f};

        float hh[64];
#pragma unroll
        for (int j = 0; j < 64; ++j) hh[j] = 0.f;
#pragma unroll 1
        for (int c = 0; c < 4; ++c) {
#pragma unroll
            for (int li = 0; li < 4; ++li) {
                int l = c * 4 + li;
                float f0, f1;
                enc_level(ux, uy, uz, RESF[l], htab + (size_t)l * (TSZ * 2), f0, f1);
                buf[(2 * li) * 256 + tid] = f0;
                buf[(2 * li + 1) * 256 + tid] = f1;
            }
#pragma unroll 1
            for (int k2 = 0; k2 < 8; ++k2) {
                float e = buf[k2 * 256 + tid];
                const float* wrow = &L[(c * 8 + k2) * 64];
#pragma unroll
                for (int jq = 0; jq < 16; ++jq) {
                    float4 wv = *(const float4*)(wrow + jq * 4);
                    hh[jq * 4 + 0] = fmaf(e, wv.x, hh[jq * 4 + 0]);
                    hh[jq * 4 + 1] = fmaf(e, wv.y, hh[jq * 4 + 1]);
                    hh[jq * 4 + 2] = fmaf(e, wv.z, hh[jq * 4 + 2]);
                    hh[jq * 4 + 3] = fmaf(e, wv.w, hh[jq * 4 + 3]);
                }
            }
        }

#pragma unroll
        for (int j = 0; j < 17; ++j) acc[j] = 0.f;
#pragma unroll
        for (int c = 0; c < 8; ++c) {
#pragma unroll
            for (int q = 0; q < 8; ++q) buf[q * 256 + tid] = fmaxf(hh[c * 8 + q], 0.f);
#pragma unroll 1
            for (int k2 = 0; k2 < 8; ++k2) {
                float hv = buf[k2 * 256 + tid];
                const float* wrow = &L[2048 + (c * 8 + k2) * 20];
#pragma unroll
                for (int jq = 0; jq < 4; ++jq) {
                    float4 wv = *(const float4*)(wrow + jq * 4);
                    acc[jq * 4 + 0] = fmaf(hv, wv.x, acc[jq * 4 + 0]);
                    acc[jq * 4 + 1] = fmaf(hv, wv.y, acc[jq * 4 + 1]);
                    acc[jq * 4 + 2] = fmaf(hv, wv.z, acc[jq * 4 + 2]);
                    acc[jq * 4 + 3] = fmaf(hv, wv.w, acc[jq * 4 + 3]);
                }
                acc[16] = fmaf(hv, wrow[16], acc[16]);
            }
        }
        sigma = fmaxf(acc[0], 0.f);
    }

    float sd = occ ? sigma * delta : 0.f;
    out4[p] = make_float4(sd, 0.f, 0.f, 0.f);

    bool pos = occ && (sigma > 0.f);
    unsigned long long m = __ballot(pos);
    int lane = tid & 63;
    int nw = __popcll(m);
    int base = 0;
    if (lane == 0 && nw > 0) base = atomicAdd(cnt2, nw);
    base = __shfl(base, 0, 64);
    if (pos) {
        int j2 = base + __popcll(m & ((1ull << lane) - 1ull));
        plist2[j2] = p;
        gst4[(size_t)j2 * 4 + 0] = make_float4(acc[1], acc[2], acc[3], acc[4]);
        gst4[(size_t)j2 * 4 + 1] = make_float4(acc[5], acc[6], acc[7], acc[8]);
        gst4[(size_t)j2 * 4 + 2] = make_float4(acc[9], acc[10], acc[11], acc[12]);
        gst4[(size_t)j2 * 4 + 3] = make_float4(acc[13], acc[14], acc[15], acc[16]);
    }
}

// ---------------- K_rgb: rgb MLP on sigma>0-compacted points ------------------
__launch_bounds__(256)
__global__ void k_rgb(
    const float* __restrict__ rw1, const float* __restrict__ rw2,
    const float* __restrict__ rw3,
    const int* __restrict__ plist2, const int* __restrict__ cnt2,
    const float* __restrict__ h1p, const float4* __restrict__ gst4,
    float4* __restrict__ out4)
{
    __shared__ float L[7424];
    int tid = threadIdx.x;
    int c2 = cnt2[0];
    if (blockIdx.x * 256 >= c2) return;
    for (int i = tid; i < 1024; i += 256) L[i] = rw1[1024 + i];
    for (int i = tid; i < 4096; i += 256) L[1024 + i] = rw2[i];
    if (tid < 192) { int rr = tid / 3, cc = tid - rr * 3; L[5120 + rr * 4 + cc] = rw3[tid]; }
    __syncthreads();
    float* buf = L + 5376;

    int i = blockIdx.x * 256 + tid;
    bool active = i < c2;
    int ii = active ? i : 0;
    int pid = plist2[ii];
    int r = pid >> 7;

    float hh[64];
    const float4* hp4 = (const float4*)(h1p + (size_t)r * 64);
#pragma unroll
    for (int q = 0; q < 16; ++q) {
        float4 v = hp4[q];
        hh[q * 4 + 0] = v.x; hh[q * 4 + 1] = v.y; hh[q * 4 + 2] = v.z; hh[q * 4 + 3] = v.w;
    }
    float geo[16];
#pragma unroll
    for (int q = 0; q < 4; ++q) {
        float4 g = gst4[(size_t)ii * 4 + q];
        geo[q * 4 + 0] = g.x; geo[q * 4 + 1] = g.y; geo[q * 4 + 2] = g.z; geo[q * 4 + 3] = g.w;
    }

#pragma unroll
    for (int c = 0; c < 2; ++c) {
#pragma unroll
        for (int q = 0; q < 8; ++q) buf[q * 256 + tid] = geo[c * 8 + q];
#pragma unroll 1
        for (int k2 = 0; k2 < 8; ++k2) {
            float xv = buf[k2 * 256 + tid];
            const float* wrow = &L[(c * 8 + k2) * 64];
#pragma unroll
            for (int jq = 0; jq < 16; ++jq) {
                float4 wv = *(const float4*)(wrow + jq * 4);
                hh[jq * 4 + 0] = fmaf(xv, wv.x, hh[jq * 4 + 0]);
                hh[jq * 4 + 1] = fmaf(xv, wv.y, hh[jq * 4 + 1]);
                hh[jq * 4 + 2] = fmaf(xv, wv.z, hh[jq * 4 + 2]);
                hh[jq * 4 + 3] = fmaf(xv, wv.w, hh[jq * 4 + 3]);
            }
        }
    }

    float h2[64];
#pragma unroll
    for (int j = 0; j < 64; ++j) h2[j] = 0.f;
#pragma unroll
    for (int c = 0; c < 8; ++c) {
#pragma unroll
        for (int q = 0; q < 8; ++q) buf[q * 256 + tid] = fmaxf(hh[c * 8 + q], 0.f);
#pragma unroll 1
        for (int k2 = 0; k2 < 8; ++k2) {
            float hv = buf[k2 * 256 + tid];
            const float* wrow = &L[1024 + (c * 8 + k2) * 64];
#pragma unroll
            for (int jq = 0; jq < 16; ++jq) {
                float4 wv = *(const float4*)(wrow + jq * 4);
                h2[jq * 4 + 0] = fmaf(hv, wv.x, h2[jq * 4 + 0]);
                h2[jq * 4 + 1] = fmaf(hv, wv.y, h2[jq * 4 + 1]);
                h2[jq * 4 + 2] = fmaf(hv, wv.z, h2[jq * 4 + 2]);
                h2[jq * 4 + 3] = fmaf(hv, wv.w, h2[jq * 4 + 3]);
            }
        }
    }

    float o0 = 0.f, o1 = 0.f, o2 = 0.f;
#pragma unroll
    for (int k = 0; k < 64; ++k) {
        float hv = fmaxf(h2[k], 0.f);
        float4 wv = *(const float4*)&L[5120 + k * 4];
        o0 = fmaf(hv, wv.x, o0);
        o1 = fmaf(hv, wv.y, o1);
        o2 = fmaf(hv, wv.z, o2);
    }
    float r0 = 1.0f / (1.0f + expf(-o0));
    float r1 = 1.0f / (1.0f + expf(-o1));
    float r2 = 1.0f / (1.0f + expf(-o2));
    if (active) {
        float* o = (float*)&out4[pid];
        o[1] = r0; o[2] = r1; o[3] = r2;
    }
}

// ---------------- compositing: one wave per ray, shfl scan --------------------
__launch_bounds__(256)
__global__ void k_comp(const float4* __restrict__ out4, const float* __restrict__ tb,
                       const float* __restrict__ bg, float* __restrict__ out)
{
#pragma clang fp contract(off)
    int wid = threadIdx.x >> 6, lane = threadIdx.x & 63;
    int r = blockIdx.x * 4 + wid;
    double im0 = 0, im1 = 0, im2 = 0, dep = 0, aw = 0;
    float carry = 0.f;
#pragma unroll
    for (int half = 0; half < 2; ++half) {
        int p = r * 128 + half * 64 + lane;
        float4 v = out4[p];
        float tv = tb[p];
        float sd = v.x;
        float incl = sd;
#pragma unroll
        for (int off = 1; off < 64; off <<= 1) {
            float t = __shfl_up(incl, off, 64);
            if (lane >= off) incl += t;
        }
        float excl = __shfl_up(incl, 1, 64);
        if (lane == 0) excl = 0.f;
        float cum = carry + excl;
        float T = (float)exp(-(double)cum);
        float e1 = (float)exp(-(double)sd);
        float wgt = (1.0f - e1) * T;
        im0 += (double)(wgt * v.y);
        im1 += (double)(wgt * v.z);
        im2 += (double)(wgt * v.w);
        dep += (double)(wgt * tv);
        aw  += (double)wgt;
        carry = carry + __shfl(incl, 63, 64);
    }
#pragma unroll
    for (int off = 32; off > 0; off >>= 1) {
        im0 += __shfl_down(im0, off, 64);
        im1 += __shfl_down(im1, off, 64);
        im2 += __shfl_down(im2, off, 64);
        dep += __shfl_down(dep, off, 64);
        aw  += __shfl_down(aw, off, 64);
    }
    if (lane == 0) {
        float accf = (float)aw;
        out[r * 3 + 0] = (float)im0 + (1.0f - accf) * bg[0];
        out[r * 3 + 1] = (float)im1 + (1.0f - accf) * bg[1];
        out[r * 3 + 2] = (float)im2 + (1.0f - accf) * bg[2];
        out[RR * 3 + r] = (float)dep;
    }
}

// =================== FALLBACK PATH (round-1 kernel, known good) ===============
__device__ __forceinline__ void geom_fb(
    int r, int s,
    const int* __restrict__ n, const int* __restrict__ h, const int* __restrict__ w,
    const float* __restrict__ Kall, const float* __restrict__ Eall,
    const float* __restrict__ bds, const float* __restrict__ tn,
    const float* __restrict__ grid, float meanv,
    float& ux, float& uy, float& uz,
    float& ddx, float& ddy, float& ddz,
    float& tout, float& dlout, bool& occ)
{
#pragma clang fp contract(off)
    int ni = n[r];
    const float* K = Kall + ni * 9;
    const float* E = Eall + ni * 16;
    float fx = K[0], cx = K[2], fy = K[4], cy = K[5];
    float wf = (float)w[r], hf = (float)h[r];
    float dc0 = __fdiv_rn(wf + 0.5f - cx, fx);
    float dc1 = __fdiv_rn(hf + 0.5f - cy, fy);
    float dc2 = 1.0f;
    float d0 = E[0] * dc0 + E[1] * dc1 + E[2] * dc2;
    float d1 = E[4] * dc0 + E[5] * dc1 + E[6] * dc2;
    float d2 = E[8] * dc0 + E[9] * dc1 + E[10] * dc2;
    float nn = __fsqrt_rn(d0 * d0 + d1 * d1 + d2 * d2);
    d0 = __fdiv_rn(d0, nn); d1 = __fdiv_rn(d1, nn); d2 = __fdiv_rn(d2, nn);
    float ox = E[3], oy = E[7], oz = E[11];
    float nearv = bds[ni * 2 + 0], farv = bds[ni * 2 + 1];
    float sf = (float)s;
    float tcur = nearv + (farv - nearv) * ((sf + tn[r * SS + s]) / 128.0f);
    float dl;
    if (s < SS - 1) {
        float t2 = nearv + (farv - nearv) * (((sf + 1.0f) + tn[r * SS + s + 1]) / 128.0f);
        dl = t2 - tcur;
    } else {
        dl = farv - tcur;
    }
    float px = fminf(fmaxf(ox + d0 * tcur, -1.0f), 1.0f);
    float py = fminf(fmaxf(oy + d1 * tcur, -1.0f), 1.0f);
    float pz = fminf(fmaxf(oz + d2 * tcur, -1.0f), 1.0f);
    ux = (px + 1.0f) / 2.0f;
    uy = (py + 1.0f) / 2.0f;
    uz = (pz + 1.0f) / 2.0f;
    int g0 = min(max((int)(ux * 128.0f), 0), 127);
    int g1 = min(max((int)(uy * 128.0f), 0), 127);
    int g2 = min(max((int)(uz * 128.0f), 0), 127);
    occ = grid[(g0 * 128 + g1) * 128 + g2] > meanv;
    ddx = d0; ddy = d1; ddz = d2; tout = tcur; dlout = dl;
}

__launch_bounds__(256)
__global__ void k_points_fb(
    const int* __restrict__ n, const int* __restrict__ h, const int* __restrict__ w,
    const float* __restrict__ intr, const float* __restrict__ extr,
    const float* __restrict__ bds, const float* __restrict__ tn,
    const float* __restrict__ htab,
    const float* __restrict__ sw1, const float* __restrict__ sw2,
    const float* __restrict__ rw1, const float* __restrict__ rw2,
    const float* __restrict__ rw3,
    const float* __restrict__ grid, const float* __restrict__ meanf,
    float4* __restrict__ out4, float* __restrict__ tbuf)
{
    __shared__ float L[9728 + 8 * 256];
    int tid = threadIdx.x;
    for (int i = tid; i < 2048; i += 256) L[i] = sw1[i];
    for (int i = tid; i < 1088; i += 256) { int rr = i / 17, cc = i - rr * 17; L[2048 + rr * 20 + cc] = sw2[i]; }
    for (int i = tid; i < 2048; i += 256) L[3328 + i] = rw1[i];
    for (int i = tid; i < 4096; i += 256) L[5376 + i] = rw2[i];
    if (tid < 192) { int rr = tid / 3, cc = tid - rr * 3; L[9472 + rr * 4 + cc] = rw3[tid]; }
    __syncthreads();
    float* buf = L + 9728;

    int p = blockIdx.x * 256 + tid;
    int r = p >> 7, s = p & 127;
    float ux, uy, uz, d0, d1, d2, tcur, delta;
    bool occ;
    geom_fb(r, s, n, h, w, intr, extr, bds, tn, grid, meanf[0],
            ux, uy, uz, d0, d1, d2, tcur, delta, occ);

    float hh[64];
#pragma unroll
    for (int j = 0; j < 64; ++j) hh[j] = 0.f;
#pragma unroll 1
    for (int c = 0; c < 4; ++c) {
#pragma unroll 1
        for (int li = 0; li < 4; ++li) {
            int l = c * 4 + li;
            float f0, f1;
            enc_level(ux, uy, uz, RESF_G[l], htab + (size_t)l * (TSZ * 2), f0, f1);
            buf[(2 * li) * 256 + tid] = f0;
            buf[(2 * li + 1) * 256 + tid] = f1;
        }
#pragma unroll 1
        for (int k2 = 0; k2 < 8; ++k2) {
            float e = buf[k2 * 256 + tid];
            const float* wrow = &L[(c * 8 + k2) * 64];
#pragma unroll
            for (int jq = 0; jq < 16; ++jq) {
                float4 wv = *(const float4*)(wrow + jq * 4);
                hh[jq * 4 + 0] = fmaf(e, wv.x, hh[jq * 4 + 0]);
                hh[jq * 4 + 1] = fmaf(e, wv.y, hh[jq * 4 + 1]);
                hh[jq * 4 + 2] = fmaf(e, wv.z, hh[jq * 4 + 2]);
                hh[jq * 4 + 3] = fmaf(e, wv.w, hh[jq * 4 + 3]);
            }
        }
    }
    float acc[17];
#pragma unroll
    for (int j = 0; j < 17; ++j) acc[j] = 0.f;
#pragma unroll
    for (int c = 0; c < 8; ++c) {
#pragma unroll
        for (int q = 0; q < 8; ++q) buf[q * 256 + tid] = fmaxf(hh[c * 8 + q], 0.f);
#pragma unroll 1
        for (int k2 = 0; k2 < 8; ++k2) {
            float hv = buf[k2 * 256 + tid];
            const float* wrow = &L[2048 + (c * 8 + k2) * 20];
#pragma unroll
            for (int jq = 0; jq < 4; ++jq) {
                float4 wv = *(const float4*)(wrow + jq * 4);
                acc[jq * 4 + 0] = fmaf(hv, wv.x, acc[jq * 4 + 0]);
                acc[jq * 4 + 1] = fmaf(hv, wv.y, acc[jq * 4 + 1]);
                acc[jq * 4 + 2] = fmaf(hv, wv.z, acc[jq * 4 + 2]);
                acc[jq * 4 + 3] = fmaf(hv, wv.w, acc[jq * 4 + 3]);
            }
            acc[16] = fmaf(hv, wrow[16], acc[16]);
        }
    }
    float sigma = occ ? fmaxf(acc[0], 0.f) : 0.f;

    float X = d0, Y = d1, Z = d2;
    float xx = X * X, yy = Y * Y, zz = Z * Z;
    float sh[16];
    sh[0] = 0.28209479177387814f;
    sh[1] = -0.48860251190291987f * Y;
    sh[2] = 0.48860251190291987f * Z;
    sh[3] = -0.48860251190291987f * X;
    sh[4] = 1.0925484305920792f * X * Y;
    sh[5] = -1.0925484305920792f * Y * Z;
    sh[6] = 0.94617469575756f * zz - 0.31539156525252005f;
    sh[7] = -1.0925484305920792f * X * Z;
    sh[8] = 0.5462742152960396f * (xx - yy);
    sh[9] = -0.5900435899266435f * Y * (3.0f * xx - yy);
    sh[10] = 2.890611442640554f * X * Y * Z;
    sh[11] = 0.4570457994644657f * Y * (1.0f - 5.0f * zz);
    sh[12] = 0.3731763325901154f * Z * (5.0f * zz - 3.0f);
    sh[13] = 0.4570457994644657f * X * (1.0f - 5.0f * zz);
    sh[14] = 1.445305721320277f * Z * (xx - yy);
    sh[15] = -0.5900435899266435f * X * (xx - 3.0f * yy);

#pragma unroll
    for (int j = 0; j < 64; ++j) hh[j] = 0.f;
#pragma unroll
    for (int c = 0; c < 4; ++c) {
#pragma unroll
        for (int q = 0; q < 8; ++q) {
            int k = c * 8 + q;
            float xv = (k < 16) ? sh[k & 15] : acc[1 + (k - 16)];
            buf[q * 256 + tid] = xv;
        }
#pragma unroll 1
        for (int k2 = 0; k2 < 8; ++k2) {
            float xv = buf[k2 * 256 + tid];
            const float* wrow = &L[3328 + (c * 8 + k2) * 64];
#pragma unroll
            for (int jq = 0; jq < 16; ++jq) {
                float4 wv = *(const float4*)(wrow + jq * 4);
                hh[jq * 4 + 0] = fmaf(xv, wv.x, hh[jq * 4 + 0]);
                hh[jq * 4 + 1] = fmaf(xv, wv.y, hh[jq * 4 + 1]);
                hh[jq * 4 + 2] = fmaf(xv, wv.z, hh[jq * 4 + 2]);
                hh[jq * 4 + 3] = fmaf(xv, wv.w, hh[jq * 4 + 3]);
            }
        }
    }
    float h2[64];
#pragma unroll
    for (int j = 0; j < 64; ++j) h2[j] = 0.f;
#pragma unroll
    for (int c = 0; c < 8; ++c) {
#pragma unroll
        for (int q = 0; q < 8; ++q) buf[q * 256 + tid] = fmaxf(hh[c * 8 + q], 0.f);
#pragma unroll 1
        for (int k2 = 0; k2 < 8; ++k2) {
            float hv = buf[k2 * 256 + tid];
            const float* wrow = &L[5376 + (c * 8 + k2) * 64];
#pragma unroll
            for (int jq = 0; jq < 16; ++jq) {
                float4 wv = *(const float4*)(wrow + jq * 4);
                h2[jq * 4 + 0] = fmaf(hv, wv.x, h2[jq * 4 + 0]);
                h2[jq * 4 + 1] = fmaf(hv, wv.y, h2[jq * 4 + 1]);
                h2[jq * 4 + 2] = fmaf(hv, wv.z, h2[jq * 4 + 2]);
                h2[jq * 4 + 3] = fmaf(hv, wv.w, h2[jq * 4 + 3]);
            }
        }
    }
    float o0 = 0.f, o1 = 0.f, o2 = 0.f;
#pragma unroll
    for (int k = 0; k < 64; ++k) {
        float hv = fmaxf(h2[k], 0.f);
        float4 wv = *(const float4*)&L[9472 + k * 4];
        o0 = fmaf(hv, wv.x, o0);
        o1 = fmaf(hv, wv.y, o1);
        o2 = fmaf(hv, wv.z, o2);
    }
    float r0 = 1.0f / (1.0f + expf(-o0));
    float r1 = 1.0f / (1.0f + expf(-o1));
    float r2 = 1.0f / (1.0f + expf(-o2));

    float4 ov;
    ov.x = sigma * delta;
    ov.y = r0; ov.z = r1; ov.w = r2;
    out4[p] = ov;
    tbuf[p] = tcur;
}

__global__ void k_rays_fb(const float4* __restrict__ pt4, const float* __restrict__ tb,
                          const float* __restrict__ bg, float* __restrict__ out)
{
    int r = blockIdx.x * blockDim.x + threadIdx.x;
    if (r >= RR) return;
    float cum = 0.f;
    double im0 = 0, im1 = 0, im2 = 0, dep = 0, aw = 0;
    for (int s = 0; s < SS; ++s) {
        float4 v = pt4[r * SS + s];
        float tv = tb[r * SS + s];
        float T = (float)exp(-(double)cum);
        float e = (float)exp(-(double)v.x);
        float wgt = (1.0f - e) * T;
        im0 += (double)(wgt * v.y);
        im1 += (double)(wgt * v.z);
        im2 += (double)(wgt * v.w);
        dep += (double)(wgt * tv);
        aw  += (double)wgt;
        cum += v.x;
    }
    float accf = (float)aw;
    out[r * 3 + 0] = (float)im0 + (1.0f - accf) * bg[0];
    out[r * 3 + 1] = (float)im1 + (1.0f - accf) * bg[1];
    out[r * 3 + 2] = (float)im2 + (1.0f - accf) * bg[2];
    out[RR * 3 + r] = (float)dep;
}

// ============================ launch =========================================
extern "C" void kernel_launch(void* const* d_in, const int* in_sizes, int n_in,
                              void* d_out, int out_size, void* d_ws, size_t ws_size,
                              hipStream_t stream) {
    const int*   n    = (const int*)d_in[0];
    const int*   h    = (const int*)d_in[1];
    const int*   w    = (const int*)d_in[2];
    const float* intr = (const float*)d_in[3];
    const float* extr = (const float*)d_in[4];
    const float* bds  = (const float*)d_in[5];
    const float* tn   = (const float*)d_in[6];
    const float* htab = (const float*)d_in[7];
    const float* sw1  = (const float*)d_in[8];
    const float* sw2  = (const float*)d_in[9];
    const float* rw1  = (const float*)d_in[10];
    const float* rw2  = (const float*)d_in[11];
    const float* rw3  = (const float*)d_in[12];
    const float* grid = (const float*)d_in[13];
    const float* bg   = (const float*)d_in[14];

    char* ws = (char*)d_ws;
    double* part   = (double*)(ws + OFF_PART);
    float*  meanf  = (float*)(ws + OFF_MEAN);
    int*    cnt    = (int*)(ws + OFF_CNT);
    float4* out4   = (float4*)(ws + OFF_OUT4);
    float*  tbuf   = (float*)(ws + OFF_TBUF);
    int*    plist  = (int*)(ws + OFF_PLIST);
    int*    plist2 = (int*)(ws + OFF_PLIST2);
    float*  rayd   = (float*)(ws + OFF_RAYD);
    float*  h1p    = (float*)(ws + OFF_H1P);
    float4* gst4   = (float4*)(ws + OFF_GST);
    float2* feat   = (float2*)(ws + OFF_FEAT);
    float*  out    = (float*)d_out;

    k_mean_part<<<dim3(256), dim3(256), 0, stream>>>(grid, part);
    k_mean_fin<<<dim3(1), dim3(256), 0, stream>>>(part, meanf, cnt);

    if (ws_size >= WS_NEED2) {
        // XCD level-pinned split-encode path
        k_ray_pre<<<dim3(RR / 4), dim3(256), 0, stream>>>(
            n, h, w, intr, extr, bds, rw1, rayd, h1p);
        k_classify<<<dim3(PP / 256), dim3(256), 0, stream>>>(
            tn, rayd, grid, meanf, tbuf, out4, plist, cnt);
        k_enc<<<dim3(8, PP / 256), dim3(256), 0, stream>>>(
            tn, rayd, htab, plist, cnt, feat, 0);
        k_enc<<<dim3(8, PP / 256), dim3(256), 0, stream>>>(
            tn, rayd, htab, plist, cnt, feat, 8);
        k_sig<<<dim3(PP / 256), dim3(256), 0, stream>>>(
            tn, rayd, sw1, sw2, plist, cnt, cnt + 1, out4, plist2, gst4, feat);
        k_rgb<<<dim3(PP / 256), dim3(256), 0, stream>>>(
            rw1, rw2, rw3, plist2, cnt + 1, h1p, gst4, out4);
        k_comp<<<dim3(RR / 4), dim3(256), 0, stream>>>(out4, tbuf, bg, out);
    } else if (ws_size >= WS_NEED) {
        // round-6 fused path
        k_ray_pre<<<dim3(RR / 4), dim3(256), 0, stream>>>(
            n, h, w, intr, extr, bds, rw1, rayd, h1p);
        k_sigall<<<dim3(PP / 256), dim3(256), 0, stream>>>(
            tn, rayd, grid, meanf, htab, sw1, sw2, cnt + 1, out4, tbuf, plist2, gst4);
        k_rgb<<<dim3(PP / 256), dim3(256), 0, stream>>>(
            rw1, rw2, rw3, plist2, cnt + 1, h1p, gst4, out4);
        k_comp<<<dim3(RR / 4), dim3(256), 0, stream>>>(out4, tbuf, bg, out);
    } else {
        k_points_fb<<<dim3(PP / 256), dim3(256), 0, stream>>>(
            n, h, w, intr, extr, bds, tn, htab, sw1, sw2, rw1, rw2, rw3,
            grid, meanf, out4, tbuf);
        k_rays_fb<<<dim3((RR + 255) / 256), dim3(256), 0, stream>>>(out4, tbuf, bg, out);
    }
}

// Round 9
// 256.926 us; speedup vs baseline: 3.5742x; 1.4711x over previous
//
#include <hip/hip_runtime.h>
#include <math.h>

#define RR 4096
#define SS 128
#define PP (RR*SS)
#define TSZ (1u<<19)
#define TMASK (TSZ-1u)

// ---------------- workspace layout ----------------
#define OFF_PART   0                            // 256 doubles
#define OFF_MEAN   2048                         // 1 float
#define OFF_CNT    2304                         // 2 ints
#define OFF_OUT4   4096                         // PP float4 = 8 MB (sd, r, g, b)
#define OFF_TBUF   (OFF_OUT4 + (size_t)PP*16)   // PP float = 2 MB
#define OFF_PLIST  (OFF_TBUF + (size_t)PP*4)    // PP int   = 2 MB
#define OFF_PLIST2 (OFF_PLIST + (size_t)PP*4)   // PP int   = 2 MB
#define OFF_RAYD   (OFF_PLIST2 + (size_t)PP*4)  // RR*8 floats = 128 KB
#define OFF_H1P    (OFF_RAYD + (size_t)RR*32)   // RR*64 floats = 1 MB
#define OFF_GST    (OFF_H1P + (size_t)RR*256)   // PP*16 floats = 33.5 MB worst
#define WS_NEED    (OFF_GST + (size_t)PP*64)
#define OFF_FEAT   (OFF_GST + (size_t)PP*64)    // PP*16 float2 = 67 MB worst
#define WS_NEED2   (OFF_FEAT + (size_t)PP*128)

__device__ const float RESF_G[16] = {
    16.f, 22.f, 30.f, 42.f, 58.f, 80.f, 111.f, 153.f,
    212.f, 294.f, 406.f, 561.f, 775.f, 1072.f, 1481.f, 2047.f};

// ---------------- mean of density grid (deterministic, fp64) ----------------
__global__ void k_mean_part(const float* __restrict__ g, double* __restrict__ part) {
    __shared__ double sm[256];
    int tid = threadIdx.x;
    double s = 0.0;
    for (int i = blockIdx.x * 256 + tid; i < 128 * 128 * 128; i += 256 * 256)
        s += (double)g[i];
    sm[tid] = s;
    __syncthreads();
    for (int off = 128; off > 0; off >>= 1) {
        if (tid < off) sm[tid] += sm[tid + off];
        __syncthreads();
    }
    if (tid == 0) part[blockIdx.x] = sm[0];
}

__global__ void k_mean_fin(const double* __restrict__ part, float* __restrict__ meanf,
                           int* __restrict__ cnt) {
    __shared__ double sm[256];
    int tid = threadIdx.x;
    sm[tid] = part[tid];
    __syncthreads();
    for (int off = 128; off > 0; off >>= 1) {
        if (tid < off) sm[tid] += sm[tid + off];
        __syncthreads();
    }
    if (tid == 0) {
        meanf[0] = (float)(sm[0] / 2097152.0);
        cnt[0] = 0; cnt[1] = 0;
    }
}

// ---------------- per-ray geometry (bitwise-matches reference f32) ----------
__device__ __forceinline__ void ray_geom(
    int r, const int* __restrict__ n, const int* __restrict__ h, const int* __restrict__ w,
    const float* __restrict__ Kall, const float* __restrict__ Eall,
    const float* __restrict__ bds,
    float& d0, float& d1, float& d2, float& ox, float& oy, float& oz,
    float& nearv, float& farv)
{
#pragma clang fp contract(off)
    int ni = n[r];
    const float* K = Kall + ni * 9;
    const float* E = Eall + ni * 16;
    float fx = K[0], cx = K[2], fy = K[4], cy = K[5];
    float wf = (float)w[r], hf = (float)h[r];
    float dc0 = __fdiv_rn(wf + 0.5f - cx, fx);
    float dc1 = __fdiv_rn(hf + 0.5f - cy, fy);
    float dc2 = 1.0f;
    float e0 = E[0] * dc0 + E[1] * dc1 + E[2] * dc2;
    float e1 = E[4] * dc0 + E[5] * dc1 + E[6] * dc2;
    float e2 = E[8] * dc0 + E[9] * dc1 + E[10] * dc2;
    float nn = __fsqrt_rn(e0 * e0 + e1 * e1 + e2 * e2);
    d0 = __fdiv_rn(e0, nn); d1 = __fdiv_rn(e1, nn); d2 = __fdiv_rn(e2, nn);
    ox = E[3]; oy = E[7]; oz = E[11];
    nearv = bds[ni * 2 + 0]; farv = bds[ni * 2 + 1];
}

// per-point t / delta / normalized coords (bitwise-stable, shared by kernels)
__device__ __forceinline__ void point_u(
    int s, int p, const float* __restrict__ rd, const float* __restrict__ tn,
    float& ux, float& uy, float& uz, float& tcur, float& delta)
{
#pragma clang fp contract(off)
    float d0 = rd[0], d1 = rd[1], d2 = rd[2];
    float ox = rd[3], oy = rd[4], oz = rd[5];
    float nearv = rd[6], farv = rd[7];
    float sf = (float)s;
    tcur = nearv + (farv - nearv) * ((sf + tn[p]) / 128.0f);
    if (s < SS - 1) {
        float t2 = nearv + (farv - nearv) * (((sf + 1.0f) + tn[p + 1]) / 128.0f);
        delta = t2 - tcur;
    } else {
        delta = farv - tcur;
    }
    float px = fminf(fmaxf(ox + d0 * tcur, -1.0f), 1.0f);
    float py = fminf(fmaxf(oy + d1 * tcur, -1.0f), 1.0f);
    float pz = fminf(fmaxf(oz + d2 * tcur, -1.0f), 1.0f);
    ux = (px + 1.0f) / 2.0f;
    uy = (py + 1.0f) / 2.0f;
    uz = (pz + 1.0f) / 2.0f;
}

// one hash-grid level; corner order/rounding matches reference exactly
__device__ __forceinline__ void enc_level(
    float ux, float uy, float uz, float res,
    const float* __restrict__ tab, float& f0, float& f1)
{
#pragma clang fp contract(off)
    float px = ux * res, py = uy * res, pz = uz * res;
    float p0x = floorf(px), p0y = floorf(py), p0z = floorf(pz);
    float fxx = px - p0x, fyy = py - p0y, fzz = pz - p0z;
    unsigned x0 = (unsigned)p0x, y0 = (unsigned)p0y, z0 = (unsigned)p0z;
    f0 = 0.f; f1 = 0.f;
    const float2* t2 = (const float2*)tab;
#pragma unroll
    for (int dx = 0; dx < 2; ++dx) {
        unsigned cxi = x0 + (unsigned)dx;
        float wx = dx ? fxx : 1.0f - fxx;
#pragma unroll
        for (int dy = 0; dy < 2; ++dy) {
            unsigned hy = (y0 + (unsigned)dy) * 2654435761u;
            float wy = dy ? fyy : 1.0f - fyy;
#pragma unroll
            for (int dz = 0; dz < 2; ++dz) {
                unsigned hz = (z0 + (unsigned)dz) * 805459861u;
                float wz = dz ? fzz : 1.0f - fzz;
                unsigned hh = (cxi ^ hy ^ hz) & TMASK;
                float2 tv = t2[hh];
                float ww = (wx * wy) * wz;
                f0 = f0 + tv.x * ww;
                f1 = f1 + tv.y * ww;
            }
        }
    }
}

// ---------------- K_ray: per-ray dir/origin/bounds + SH partial of rgb MLP ----
__launch_bounds__(256)
__global__ void k_ray_pre(
    const int* __restrict__ n, const int* __restrict__ h, const int* __restrict__ w,
    const float* __restrict__ intr, const float* __restrict__ extr,
    const float* __restrict__ bds, const float* __restrict__ rw1,
    float* __restrict__ rayd, float* __restrict__ h1p)
{
#pragma clang fp contract(off)
    int wid = threadIdx.x >> 6, lane = threadIdx.x & 63;
    int r = blockIdx.x * 4 + wid;
    float d0, d1, d2, ox, oy, oz, nearv, farv;
    ray_geom(r, n, h, w, intr, extr, bds, d0, d1, d2, ox, oy, oz, nearv, farv);

    float X = d0, Y = d1, Z = d2;
    float xx = X * X, yy = Y * Y, zz = Z * Z;
    float sh[16];
    sh[0] = 0.28209479177387814f;
    sh[1] = -0.48860251190291987f * Y;
    sh[2] = 0.48860251190291987f * Z;
    sh[3] = -0.48860251190291987f * X;
    sh[4] = 1.0925484305920792f * X * Y;
    sh[5] = -1.0925484305920792f * Y * Z;
    sh[6] = 0.94617469575756f * zz - 0.31539156525252005f;
    sh[7] = -1.0925484305920792f * X * Z;
    sh[8] = 0.5462742152960396f * (xx - yy);
    sh[9] = -0.5900435899266435f * Y * (3.0f * xx - yy);
    sh[10] = 2.890611442640554f * X * Y * Z;
    sh[11] = 0.4570457994644657f * Y * (1.0f - 5.0f * zz);
    sh[12] = 0.3731763325901154f * Z * (5.0f * zz - 3.0f);
    sh[13] = 0.4570457994644657f * X * (1.0f - 5.0f * zz);
    sh[14] = 1.445305721320277f * Z * (xx - yy);
    sh[15] = -0.5900435899266435f * X * (xx - 3.0f * yy);

    float acc = 0.f;
#pragma unroll
    for (int k = 0; k < 16; ++k)
        acc = fmaf(sh[k], rw1[k * 64 + lane], acc);
    h1p[r * 64 + lane] = acc;

    if (lane == 0) {
        float* rd = rayd + r * 8;
        rd[0] = d0; rd[1] = d1; rd[2] = d2;
        rd[3] = ox; rd[4] = oy; rd[5] = oz;
        rd[6] = nearv; rd[7] = farv;
    }
}

// ---------------- K_classify: occ test + BLOCK-aggregated compaction ----------
// R8 lesson: per-wave same-address atomicAdd = 8192 atomics ~ 12 ns each = 98 us.
// 1024-thread blocks + LDS wave-count prefix + ONE atomic per block -> 512 atomics.
__launch_bounds__(1024)
__global__ void k_classify(
    const float* __restrict__ tn, const float* __restrict__ rayd,
    const float* __restrict__ grid, const float* __restrict__ meanf,
    float* __restrict__ tbuf, float4* __restrict__ out4,
    int* __restrict__ plist, int* __restrict__ cnt)
{
#pragma clang fp contract(off)
    int p = blockIdx.x * 1024 + threadIdx.x;
    int r = p >> 7, s = p & 127;
    const float* rd = rayd + r * 8;
    float ux, uy, uz, tcur, delta;
    point_u(s, p, rd, tn, ux, uy, uz, tcur, delta);
    int g0 = min(max((int)(ux * 128.0f), 0), 127);
    int g1 = min(max((int)(uy * 128.0f), 0), 127);
    int g2 = min(max((int)(uz * 128.0f), 0), 127);
    bool occ = grid[(g0 * 128 + g1) * 128 + g2] > meanf[0];

    tbuf[p] = tcur;
    out4[p] = make_float4(0.f, 0.f, 0.f, 0.f);

    __shared__ int s_wcnt[16];
    __shared__ int s_base;
    int wid = threadIdx.x >> 6, lane = threadIdx.x & 63;
    unsigned long long m = __ballot(occ);
    int nw = __popcll(m);
    if (lane == 0) s_wcnt[wid] = nw;
    __syncthreads();
    if (threadIdx.x == 0) {
        int t = 0;
#pragma unroll
        for (int k = 0; k < 16; ++k) { int v = s_wcnt[k]; s_wcnt[k] = t; t += v; }
        s_base = (t > 0) ? atomicAdd(&cnt[0], t) : 0;
    }
    __syncthreads();
    if (occ) {
        int idx = s_base + s_wcnt[wid] + __popcll(m & ((1ull << lane) - 1ull));
        plist[idx] = p;
    }
}

// ===== K_enc: one hash level per block.x; XCD-pinned (grid(8,NB), x fastest =>
// linear_bid%8 == blockIdx.x == XCD). Each XCD's level table (4 MB) stays
// resident in its private L2. Two launches cover levels 0-7 and 8-15.
__launch_bounds__(256)
__global__ void k_enc(
    const float* __restrict__ tn, const float* __restrict__ rayd,
    const float* __restrict__ htab,
    const int* __restrict__ plist, const int* __restrict__ cnt,
    float2* __restrict__ feat, int lvl_base)
{
#pragma clang fp contract(off)
    int cnt0 = cnt[0];
    int j0 = blockIdx.y * 256;
    if (j0 >= cnt0) return;
    int l = lvl_base + blockIdx.x;
    int j = j0 + threadIdx.x;
    bool active = j < cnt0;
    int pid = plist[active ? j : 0];
    int r = pid >> 7, s = pid & 127;
    const float* rd = rayd + r * 8;
    float ux, uy, uz, tcur, delta;
    point_u(s, pid, rd, tn, ux, uy, uz, tcur, delta);
    float f0, f1;
    enc_level(ux, uy, uz, RESF_G[l], htab + (size_t)l * (TSZ * 2), f0, f1);
    if (active) feat[(size_t)l * PP + j] = make_float2(f0, f1);
}

// ===== K_sig: R2-proven register shape; features from feat buffer ===========
// Block-aggregated sigma>0 compaction (1 atomic per 256-thread block).
__launch_bounds__(256)
__global__ void k_sig(
    const float* __restrict__ tn, const float* __restrict__ rayd,
    const float* __restrict__ sw1, const float* __restrict__ sw2,
    const int* __restrict__ plist, const int* __restrict__ cnt,
    int* __restrict__ cnt2,
    float4* __restrict__ out4, int* __restrict__ plist2, float4* __restrict__ gst4,
    const float2* __restrict__ feat)
{
    __shared__ float L[5376];   // sw1 32x64 | sw2 64 rows stride 20 | buf 8x256
    __shared__ int s_wcnt[4];
    __shared__ int s_base;
    int tid = threadIdx.x;
    int cnt0 = cnt[0];
    if (blockIdx.x * 256 >= cnt0) return;
    for (int i = tid; i < 2048; i += 256) L[i] = sw1[i];
    for (int i = tid; i < 1088; i += 256) { int rr = i / 17, cc = i - rr * 17; L[2048 + rr * 20 + cc] = sw2[i]; }
    __syncthreads();
    float* buf = L + 3328;

    int i = blockIdx.x * 256 + tid;
    bool active = i < cnt0;
    int ii = active ? i : 0;
    int pid = plist[ii];
    int r = pid >> 7, s = pid & 127;

    const float* rd = rayd + r * 8;
    float ux, uy, uz, tcur, delta;
    point_u(s, pid, rd, tn, ux, uy, uz, tcur, delta);

    // ---- M1: feat (level order) -> LDS buf -> hh[64]; exact R2 structure ----
    float hh[64];
#pragma unroll
    for (int j = 0; j < 64; ++j) hh[j] = 0.f;
#pragma unroll 1
    for (int c = 0; c < 4; ++c) {
#pragma unroll
        for (int li = 0; li < 4; ++li) {
            float2 f = feat[(size_t)(c * 4 + li) * PP + ii];
            buf[(2 * li) * 256 + tid] = f.x;
            buf[(2 * li + 1) * 256 + tid] = f.y;
        }
#pragma unroll 1
        for (int k2 = 0; k2 < 8; ++k2) {
            float e = buf[k2 * 256 + tid];
            const float* wrow = &L[(c * 8 + k2) * 64];
#pragma unroll
            for (int jq = 0; jq < 16; ++jq) {
                float4 wv = *(const float4*)(wrow + jq * 4);
                hh[jq * 4 + 0] = fmaf(e, wv.x, hh[jq * 4 + 0]);
                hh[jq * 4 + 1] = fmaf(e, wv.y, hh[jq * 4 + 1]);
                hh[jq * 4 + 2] = fmaf(e, wv.z, hh[jq * 4 + 2]);
                hh[jq * 4 + 3] = fmaf(e, wv.w, hh[jq * 4 + 3]);
            }
        }
    }

    // ---- M2: relu(h)(64) @ sigma_w2(64x17); exact R2 structure ----
    float acc[17];
#pragma unroll
    for (int j = 0; j < 17; ++j) acc[j] = 0.f;
#pragma unroll
    for (int c = 0; c < 8; ++c) {
#pragma unroll
        for (int q = 0; q < 8; ++q) buf[q * 256 + tid] = fmaxf(hh[c * 8 + q], 0.f);
#pragma unroll 1
        for (int k2 = 0; k2 < 8; ++k2) {
            float hv = buf[k2 * 256 + tid];
            const float* wrow = &L[2048 + (c * 8 + k2) * 20];
#pragma unroll
            for (int jq = 0; jq < 4; ++jq) {
                float4 wv = *(const float4*)(wrow + jq * 4);
                acc[jq * 4 + 0] = fmaf(hv, wv.x, acc[jq * 4 + 0]);
                acc[jq * 4 + 1] = fmaf(hv, wv.y, acc[jq * 4 + 1]);
                acc[jq * 4 + 2] = fmaf(hv, wv.z, acc[jq * 4 + 2]);
                acc[jq * 4 + 3] = fmaf(hv, wv.w, acc[jq * 4 + 3]);
            }
            acc[16] = fmaf(hv, wrow[16], acc[16]);
        }
    }

    float sigma = fmaxf(acc[0], 0.f);     // occ known true for active lanes
    float sd = sigma * delta;
    if (active) ((float*)out4)[(size_t)pid * 4] = sd;

    bool pos = active && (sigma > 0.f);
    int wid = tid >> 6, lane = tid & 63;
    unsigned long long m = __ballot(pos);
    int nw = __popcll(m);
    if (lane == 0) s_wcnt[wid] = nw;
    __syncthreads();
    if (tid == 0) {
        int t = 0;
#pragma unroll
        for (int k = 0; k < 4; ++k) { int v = s_wcnt[k]; s_wcnt[k] = t; t += v; }
        s_base = (t > 0) ? atomicAdd(cnt2, t) : 0;
    }
    __syncthreads();
    if (pos) {
        int j2 = s_base + s_wcnt[wid] + __popcll(m & ((1ull << lane) - 1ull));
        plist2[j2] = pid;
        gst4[(size_t)j2 * 4 + 0] = make_float4(acc[1], acc[2], acc[3], acc[4]);
        gst4[(size_t)j2 * 4 + 1] = make_float4(acc[5], acc[6], acc[7], acc[8]);
        gst4[(size_t)j2 * 4 + 2] = make_float4(acc[9], acc[10], acc[11], acc[12]);
        gst4[(size_t)j2 * 4 + 3] = make_float4(acc[13], acc[14], acc[15], acc[16]);
    }
}

// ===== K_sigall (round-6 path, used when ws too small for feat buffer) =======
__launch_bounds__(256)
__global__ void k_sigall(
    const float* __restrict__ tn, const float* __restrict__ rayd,
    const float* __restrict__ grid, const float* __restrict__ meanf,
    const float* __restrict__ htab,
    const float* __restrict__ sw1, const float* __restrict__ sw2,
    int* __restrict__ cnt2,
    float4* __restrict__ out4, float* __restrict__ tbuf,
    int* __restrict__ plist2, float4* __restrict__ gst4)
{
    __shared__ float L[5376];
    __shared__ int s_wcnt[4];
    __shared__ int s_base;
    int tid = threadIdx.x;
    for (int i = tid; i < 2048; i += 256) L[i] = sw1[i];
    for (int i = tid; i < 1088; i += 256) { int rr = i / 17, cc = i - rr * 17; L[2048 + rr * 20 + cc] = sw2[i]; }
    __syncthreads();
    float* buf = L + 3328;

    int p = blockIdx.x * 256 + tid;
    int r = p >> 7, s = p & 127;
    const float* rd = rayd + r * 8;
    float ux, uy, uz, tcur, delta;
    point_u(s, p, rd, tn, ux, uy, uz, tcur, delta);

    int g0 = min(max((int)(ux * 128.0f), 0), 127);
    int g1 = min(max((int)(uy * 128.0f), 0), 127);
    int g2 = min(max((int)(uz * 128.0f), 0), 127);
    bool occ = grid[(g0 * 128 + g1) * 128 + g2] > meanf[0];
    tbuf[p] = tcur;

    float sigma = 0.f;
    float acc[17];
    if (occ) {
        const float RESF[16] = {
            16.f, 22.f, 30.f, 42.f, 58.f, 80.f, 111.f, 153.f,
            212.f, 294.f, 406.f, 561.f, 775.f, 1072.f, 1481.f, 2047.f};

        float hh[64];
#pragma unroll
        for (int j = 0; j < 64; ++j) hh[j] = 0.f;
#pragma unroll 1
        for (int c = 0; c < 4; ++c) {
#pragma unroll
            for (int li = 0; li < 4; ++li) {
                int l = c * 4 + li;
                float f0, f1;
                enc_level(ux, uy, uz, RESF[l], htab + (size_t)l * (TSZ * 2), f0, f1);
                buf[(2 * li) * 256 + tid] = f0;
                buf[(2 * li + 1) * 256 + tid] = f1;
            }
#pragma unroll 1
            for (int k2 = 0; k2 < 8; ++k2) {
                float e = buf[k2 * 256 + tid];
                const float* wrow = &L[(c * 8 + k2) * 64];
#pragma unroll
                for (int jq = 0; jq < 16; ++jq) {
                    float4 wv = *(const float4*)(wrow + jq * 4);
                    hh[jq * 4 + 0] = fmaf(e, wv.x, hh[jq * 4 + 0]);
                    hh[jq * 4 + 1] = fmaf(e, wv.y, hh[jq * 4 + 1]);
                    hh[jq * 4 + 2] = fmaf(e, wv.z, hh[jq * 4 + 2]);
                    hh[jq * 4 + 3] = fmaf(e, wv.w, hh[jq * 4 + 3]);
                }
            }
        }

#pragma unroll
        for (int j = 0; j < 17; ++j) acc[j] = 0.f;
#pragma unroll
        for (int c = 0; c < 8; ++c) {
#pragma unroll
            for (int q = 0; q < 8; ++q) buf[q * 256 + tid] = fmaxf(hh[c * 8 + q], 0.f);
#pragma unroll 1
            for (int k2 = 0; k2 < 8; ++k2) {
                float hv = buf[k2 * 256 + tid];
                const float* wrow = &L[2048 + (c * 8 + k2) * 20];
#pragma unroll
                for (int jq = 0; jq < 4; ++jq) {
                    float4 wv = *(const float4*)(wrow + jq * 4);
                    acc[jq * 4 + 0] = fmaf(hv, wv.x, acc[jq * 4 + 0]);
                    acc[jq * 4 + 1] = fmaf(hv, wv.y, acc[jq * 4 + 1]);
                    acc[jq * 4 + 2] = fmaf(hv, wv.z, acc[jq * 4 + 2]);
                    acc[jq * 4 + 3] = fmaf(hv, wv.w, acc[jq * 4 + 3]);
                }
                acc[16] = fmaf(hv, wrow[16], acc[16]);
            }
        }
        sigma = fmaxf(acc[0], 0.f);
    }

    float sd = occ ? sigma * delta : 0.f;
    out4[p] = make_float4(sd, 0.f, 0.f, 0.f);

    bool pos = occ && (sigma > 0.f);
    int wid = tid >> 6, lane = tid & 63;
    unsigned long long m = __ballot(pos);
    int nw = __popcll(m);
    if (lane == 0) s_wcnt[wid] = nw;
    __syncthreads();
    if (tid == 0) {
        int t = 0;
#pragma unroll
        for (int k = 0; k < 4; ++k) { int v = s_wcnt[k]; s_wcnt[k] = t; t += v; }
        s_base = (t > 0) ? atomicAdd(cnt2, t) : 0;
    }
    __syncthreads();
    if (pos) {
        int j2 = s_base + s_wcnt[wid] + __popcll(m & ((1ull << lane) - 1ull));
        plist2[j2] = p;
        gst4[(size_t)j2 * 4 + 0] = make_float4(acc[1], acc[2], acc[3], acc[4]);
        gst4[(size_t)j2 * 4 + 1] = make_float4(acc[5], acc[6], acc[7], acc[8]);
        gst4[(size_t)j2 * 4 + 2] = make_float4(acc[9], acc[10], acc[11], acc[12]);
        gst4[(size_t)j2 * 4 + 3] = make_float4(acc[13], acc[14], acc[15], acc[16]);
    }
}

// ---------------- K_rgb: rgb MLP on sigma>0-compacted points ------------------
__launch_bounds__(256)
__global__ void k_rgb(
    const float* __restrict__ rw1, const float* __restrict__ rw2,
    const float* __restrict__ rw3,
    const int* __restrict__ plist2, const int* __restrict__ cnt2,
    const float* __restrict__ h1p, const float4* __restrict__ gst4,
    float4* __restrict__ out4)
{
    __shared__ float L[7424];
    int tid = threadIdx.x;
    int c2 = cnt2[0];
    if (blockIdx.x * 256 >= c2) return;
    for (int i = tid; i < 1024; i += 256) L[i] = rw1[1024 + i];
    for (int i = tid; i < 4096; i += 256) L[1024 + i] = rw2[i];
    if (tid < 192) { int rr = tid / 3, cc = tid - rr * 3; L[5120 + rr * 4 + cc] = rw3[tid]; }
    __syncthreads();
    float* buf = L + 5376;

    int i = blockIdx.x * 256 + tid;
    bool active = i < c2;
    int ii = active ? i : 0;
    int pid = plist2[ii];
    int r = pid >> 7;

    float hh[64];
    const float4* hp4 = (const float4*)(h1p + (size_t)r * 64);
#pragma unroll
    for (int q = 0; q < 16; ++q) {
        float4 v = hp4[q];
        hh[q * 4 + 0] = v.x; hh[q * 4 + 1] = v.y; hh[q * 4 + 2] = v.z; hh[q * 4 + 3] = v.w;
    }
    float geo[16];
#pragma unroll
    for (int q = 0; q < 4; ++q) {
        float4 g = gst4[(size_t)ii * 4 + q];
        geo[q * 4 + 0] = g.x; geo[q * 4 + 1] = g.y; geo[q * 4 + 2] = g.z; geo[q * 4 + 3] = g.w;
    }

#pragma unroll
    for (int c = 0; c < 2; ++c) {
#pragma unroll
        for (int q = 0; q < 8; ++q) buf[q * 256 + tid] = geo[c * 8 + q];
#pragma unroll 1
        for (int k2 = 0; k2 < 8; ++k2) {
            float xv = buf[k2 * 256 + tid];
            const float* wrow = &L[(c * 8 + k2) * 64];
#pragma unroll
            for (int jq = 0; jq < 16; ++jq) {
                float4 wv = *(const float4*)(wrow + jq * 4);
                hh[jq * 4 + 0] = fmaf(xv, wv.x, hh[jq * 4 + 0]);
                hh[jq * 4 + 1] = fmaf(xv, wv.y, hh[jq * 4 + 1]);
                hh[jq * 4 + 2] = fmaf(xv, wv.z, hh[jq * 4 + 2]);
                hh[jq * 4 + 3] = fmaf(xv, wv.w, hh[jq * 4 + 3]);
            }
        }
    }

    float h2[64];
#pragma unroll
    for (int j = 0; j < 64; ++j) h2[j] = 0.f;
#pragma unroll
    for (int c = 0; c < 8; ++c) {
#pragma unroll
        for (int q = 0; q < 8; ++q) buf[q * 256 + tid] = fmaxf(hh[c * 8 + q], 0.f);
#pragma unroll 1
        for (int k2 = 0; k2 < 8; ++k2) {
            float hv = buf[k2 * 256 + tid];
            const float* wrow = &L[1024 + (c * 8 + k2) * 64];
#pragma unroll
            for (int jq = 0; jq < 16; ++jq) {
                float4 wv = *(const float4*)(wrow + jq * 4);
                h2[jq * 4 + 0] = fmaf(hv, wv.x, h2[jq * 4 + 0]);
                h2[jq * 4 + 1] = fmaf(hv, wv.y, h2[jq * 4 + 1]);
                h2[jq * 4 + 2] = fmaf(hv, wv.z, h2[jq * 4 + 2]);
                h2[jq * 4 + 3] = fmaf(hv, wv.w, h2[jq * 4 + 3]);
            }
        }
    }

    float o0 = 0.f, o1 = 0.f, o2 = 0.f;
#pragma unroll
    for (int k = 0; k < 64; ++k) {
        float hv = fmaxf(h2[k], 0.f);
        float4 wv = *(const float4*)&L[5120 + k * 4];
        o0 = fmaf(hv, wv.x, o0);
        o1 = fmaf(hv, wv.y, o1);
        o2 = fmaf(hv, wv.z, o2);
    }
    float r0 = 1.0f / (1.0f + expf(-o0));
    float r1 = 1.0f / (1.0f + expf(-o1));
    float r2 = 1.0f / (1.0f + expf(-o2));
    if (active) {
        float* o = (float*)&out4[pid];
        o[1] = r0; o[2] = r1; o[3] = r2;
    }
}

// ---------------- compositing: one wave per ray, shfl scan --------------------
__launch_bounds__(256)
__global__ void k_comp(const float4* __restrict__ out4, const float* __restrict__ tb,
                       const float* __restrict__ bg, float* __restrict__ out)
{
#pragma clang fp contract(off)
    int wid = threadIdx.x >> 6, lane = threadIdx.x & 63;
    int r = blockIdx.x * 4 + wid;
    double im0 = 0, im1 = 0, im2 = 0, dep = 0, aw = 0;
    float carry = 0.f;
#pragma unroll
    for (int half = 0; half < 2; ++half) {
        int p = r * 128 + half * 64 + lane;
        float4 v = out4[p];
        float tv = tb[p];
        float sd = v.x;
        float incl = sd;
#pragma unroll
        for (int off = 1; off < 64; off <<= 1) {
            float t = __shfl_up(incl, off, 64);
            if (lane >= off) incl += t;
        }
        float excl = __shfl_up(incl, 1, 64);
        if (lane == 0) excl = 0.f;
        float cum = carry + excl;
        float T = (float)exp(-(double)cum);
        float e1 = (float)exp(-(double)sd);
        float wgt = (1.0f - e1) * T;
        im0 += (double)(wgt * v.y);
        im1 += (double)(wgt * v.z);
        im2 += (double)(wgt * v.w);
        dep += (double)(wgt * tv);
        aw  += (double)wgt;
        carry = carry + __shfl(incl, 63, 64);
    }
#pragma unroll
    for (int off = 32; off > 0; off >>= 1) {
        im0 += __shfl_down(im0, off, 64);
        im1 += __shfl_down(im1, off, 64);
        im2 += __shfl_down(im2, off, 64);
        dep += __shfl_down(dep, off, 64);
        aw  += __shfl_down(aw, off, 64);
    }
    if (lane == 0) {
        float accf = (float)aw;
        out[r * 3 + 0] = (float)im0 + (1.0f - accf) * bg[0];
        out[r * 3 + 1] = (float)im1 + (1.0f - accf) * bg[1];
        out[r * 3 + 2] = (float)im2 + (1.0f - accf) * bg[2];
        out[RR * 3 + r] = (float)dep;
    }
}

// =================== FALLBACK PATH (round-1 kernel, known good) ===============
__device__ __forceinline__ void geom_fb(
    int r, int s,
    const int* __restrict__ n, const int* __restrict__ h, const int* __restrict__ w,
    const float* __restrict__ Kall, const float* __restrict__ Eall,
    const float* __restrict__ bds, const float* __restrict__ tn,
    const float* __restrict__ grid, float meanv,
    float& ux, float& uy, float& uz,
    float& ddx, float& ddy, float& ddz,
    float& tout, float& dlout, bool& occ)
{
#pragma clang fp contract(off)
    int ni = n[r];
    const float* K = Kall + ni * 9;
    const float* E = Eall + ni * 16;
    float fx = K[0], cx = K[2], fy = K[4], cy = K[5];
    float wf = (float)w[r], hf = (float)h[r];
    float dc0 = __fdiv_rn(wf + 0.5f - cx, fx);
    float dc1 = __fdiv_rn(hf + 0.5f - cy, fy);
    float dc2 = 1.0f;
    float d0 = E[0] * dc0 + E[1] * dc1 + E[2] * dc2;
    float d1 = E[4] * dc0 + E[5] * dc1 + E[6] * dc2;
    float d2 = E[8] * dc0 + E[9] * dc1 + E[10] * dc2;
    float nn = __fsqrt_rn(d0 * d0 + d1 * d1 + d2 * d2);
    d0 = __fdiv_rn(d0, nn); d1 = __fdiv_rn(d1, nn); d2 = __fdiv_rn(d2, nn);
    float ox = E[3], oy = E[7], oz = E[11];
    float nearv = bds[ni * 2 + 0], farv = bds[ni * 2 + 1];
    float sf = (float)s;
    float tcur = nearv + (farv - nearv) * ((sf + tn[r * SS + s]) / 128.0f);
    float dl;
    if (s < SS - 1) {
        float t2 = nearv + (farv - nearv) * (((sf + 1.0f) + tn[r * SS + s + 1]) / 128.0f);
        dl = t2 - tcur;
    } else {
        dl = farv - tcur;
    }
    float px = fminf(fmaxf(ox + d0 * tcur, -1.0f), 1.0f);
    float py = fminf(fmaxf(oy + d1 * tcur, -1.0f), 1.0f);
    float pz = fminf(fmaxf(oz + d2 * tcur, -1.0f), 1.0f);
    ux = (px + 1.0f) / 2.0f;
    uy = (py + 1.0f) / 2.0f;
    uz = (pz + 1.0f) / 2.0f;
    int g0 = min(max((int)(ux * 128.0f), 0), 127);
    int g1 = min(max((int)(uy * 128.0f), 0), 127);
    int g2 = min(max((int)(uz * 128.0f), 0), 127);
    occ = grid[(g0 * 128 + g1) * 128 + g2] > meanv;
    ddx = d0; ddy = d1; ddz = d2; tout = tcur; dlout = dl;
}

__launch_bounds__(256)
__global__ void k_points_fb(
    const int* __restrict__ n, const int* __restrict__ h, const int* __restrict__ w,
    const float* __restrict__ intr, const float* __restrict__ extr,
    const float* __restrict__ bds, const float* __restrict__ tn,
    const float* __restrict__ htab,
    const float* __restrict__ sw1, const float* __restrict__ sw2,
    const float* __restrict__ rw1, const float* __restrict__ rw2,
    const float* __restrict__ rw3,
    const float* __restrict__ grid, const float* __restrict__ meanf,
    float4* __restrict__ out4, float* __restrict__ tbuf)
{
    __shared__ float L[9728 + 8 * 256];
    int tid = threadIdx.x;
    for (int i = tid; i < 2048; i += 256) L[i] = sw1[i];
    for (int i = tid; i < 1088; i += 256) { int rr = i / 17, cc = i - rr * 17; L[2048 + rr * 20 + cc] = sw2[i]; }
    for (int i = tid; i < 2048; i += 256) L[3328 + i] = rw1[i];
    for (int i = tid; i < 4096; i += 256) L[5376 + i] = rw2[i];
    if (tid < 192) { int rr = tid / 3, cc = tid - rr * 3; L[9472 + rr * 4 + cc] = rw3[tid]; }
    __syncthreads();
    float* buf = L + 9728;

    int p = blockIdx.x * 256 + tid;
    int r = p >> 7, s = p & 127;
    float ux, uy, uz, d0, d1, d2, tcur, delta;
    bool occ;
    geom_fb(r, s, n, h, w, intr, extr, bds, tn, grid, meanf[0],
            ux, uy, uz, d0, d1, d2, tcur, delta, occ);

    float hh[64];
#pragma unroll
    for (int j = 0; j < 64; ++j) hh[j] = 0.f;
#pragma unroll 1
    for (int c = 0; c < 4; ++c) {
#pragma unroll 1
        for (int li = 0; li < 4; ++li) {
            int l = c * 4 + li;
            float f0, f1;
            enc_level(ux, uy, uz, RESF_G[l], htab + (size_t)l * (TSZ * 2), f0, f1);
            buf[(2 * li) * 256 + tid] = f0;
            buf[(2 * li + 1) * 256 + tid] = f1;
        }
#pragma unroll 1
        for (int k2 = 0; k2 < 8; ++k2) {
            float e = buf[k2 * 256 + tid];
            const float* wrow = &L[(c * 8 + k2) * 64];
#pragma unroll
            for (int jq = 0; jq < 16; ++jq) {
                float4 wv = *(const float4*)(wrow + jq * 4);
                hh[jq * 4 + 0] = fmaf(e, wv.x, hh[jq * 4 + 0]);
                hh[jq * 4 + 1] = fmaf(e, wv.y, hh[jq * 4 + 1]);
                hh[jq * 4 + 2] = fmaf(e, wv.z, hh[jq * 4 + 2]);
                hh[jq * 4 + 3] = fmaf(e, wv.w, hh[jq * 4 + 3]);
            }
        }
    }
    float acc[17];
#pragma unroll
    for (int j = 0; j < 17; ++j) acc[j] = 0.f;
#pragma unroll
    for (int c = 0; c < 8; ++c) {
#pragma unroll
        for (int q = 0; q < 8; ++q) buf[q * 256 + tid] = fmaxf(hh[c * 8 + q], 0.f);
#pragma unroll 1
        for (int k2 = 0; k2 < 8; ++k2) {
            float hv = buf[k2 * 256 + tid];
            const float* wrow = &L[2048 + (c * 8 + k2) * 20];
#pragma unroll
            for (int jq = 0; jq < 4; ++jq) {
                float4 wv = *(const float4*)(wrow + jq * 4);
                acc[jq * 4 + 0] = fmaf(hv, wv.x, acc[jq * 4 + 0]);
                acc[jq * 4 + 1] = fmaf(hv, wv.y, acc[jq * 4 + 1]);
                acc[jq * 4 + 2] = fmaf(hv, wv.z, acc[jq * 4 + 2]);
                acc[jq * 4 + 3] = fmaf(hv, wv.w, acc[jq * 4 + 3]);
            }
            acc[16] = fmaf(hv, wrow[16], acc[16]);
        }
    }
    float sigma = occ ? fmaxf(acc[0], 0.f) : 0.f;

    float X = d0, Y = d1, Z = d2;
    float xx = X * X, yy = Y * Y, zz = Z * Z;
    float sh[16];
    sh[0] = 0.28209479177387814f;
    sh[1] = -0.48860251190291987f * Y;
    sh[2] = 0.48860251190291987f * Z;
    sh[3] = -0.48860251190291987f * X;
    sh[4] = 1.0925484305920792f * X * Y;
    sh[5] = -1.0925484305920792f * Y * Z;
    sh[6] = 0.94617469575756f * zz - 0.31539156525252005f;
    sh[7] = -1.0925484305920792f * X * Z;
    sh[8] = 0.5462742152960396f * (xx - yy);
    sh[9] = -0.5900435899266435f * Y * (3.0f * xx - yy);
    sh[10] = 2.890611442640554f * X * Y * Z;
    sh[11] = 0.4570457994644657f * Y * (1.0f - 5.0f * zz);
    sh[12] = 0.3731763325901154f * Z * (5.0f * zz - 3.0f);
    sh[13] = 0.4570457994644657f * X * (1.0f - 5.0f * zz);
    sh[14] = 1.445305721320277f * Z * (xx - yy);
    sh[15] = -0.5900435899266435f * X * (xx - 3.0f * yy);

#pragma unroll
    for (int j = 0; j < 64; ++j) hh[j] = 0.f;
#pragma unroll
    for (int c = 0; c < 4; ++c) {
#pragma unroll
        for (int q = 0; q < 8; ++q) {
            int k = c * 8 + q;
            float xv = (k < 16) ? sh[k & 15] : acc[1 + (k - 16)];
            buf[q * 256 + tid] = xv;
        }
#pragma unroll 1
        for (int k2 = 0; k2 < 8; ++k2) {
            float xv = buf[k2 * 256 + tid];
            const float* wrow = &L[3328 + (c * 8 + k2) * 64];
#pragma unroll
            for (int jq = 0; jq < 16; ++jq) {
                float4 wv = *(const float4*)(wrow + jq * 4);
                hh[jq * 4 + 0] = fmaf(xv, wv.x, hh[jq * 4 + 0]);
                hh[jq * 4 + 1] = fmaf(xv, wv.y, hh[jq * 4 + 1]);
                hh[jq * 4 + 2] = fmaf(xv, wv.z, hh[jq * 4 + 2]);
                hh[jq * 4 + 3] = fmaf(xv, wv.w, hh[jq * 4 + 3]);
            }
        }
    }
    float h2[64];
#pragma unroll
    for (int j = 0; j < 64; ++j) h2[j] = 0.f;
#pragma unroll
    for (int c = 0; c < 8; ++c) {
#pragma unroll
        for (int q = 0; q < 8; ++q) buf[q * 256 + tid] = fmaxf(hh[c * 8 + q], 0.f);
#pragma unroll 1
        for (int k2 = 0; k2 < 8; ++k2) {
            float hv = buf[k2 * 256 + tid];
            const float* wrow = &L[5376 + (c * 8 + k2) * 64];
#pragma unroll
            for (int jq = 0; jq < 16; ++jq) {
                float4 wv = *(const float4*)(wrow + jq * 4);
                h2[jq * 4 + 0] = fmaf(hv, wv.x, h2[jq * 4 + 0]);
                h2[jq * 4 + 1] = fmaf(hv, wv.y, h2[jq * 4 + 1]);
                h2[jq * 4 + 2] = fmaf(hv, wv.z, h2[jq * 4 + 2]);
                h2[jq * 4 + 3] = fmaf(hv, wv.w, h2[jq * 4 + 3]);
            }
        }
    }
    float o0 = 0.f, o1 = 0.f, o2 = 0.f;
#pragma unroll
    for (int k = 0; k < 64; ++k) {
        float hv = fmaxf(h2[k], 0.f);
        float4 wv = *(const float4*)&L[9472 + k * 4];
        o0 = fmaf(hv, wv.x, o0);
        o1 = fmaf(hv, wv.y, o1);
        o2 = fmaf(hv, wv.z, o2);
    }
    float r0 = 1.0f / (1.0f + expf(-o0));
    float r1 = 1.0f / (1.0f + expf(-o1));
    float r2 = 1.0f / (1.0f + expf(-o2));

    float4 ov;
    ov.x = sigma * delta;
    ov.y = r0; ov.z = r1; ov.w = r2;
    out4[p] = ov;
    tbuf[p] = tcur;
}

__global__ void k_rays_fb(const float4* __restrict__ pt4, const float* __restrict__ tb,
                          const float* __restrict__ bg, float* __restrict__ out)
{
    int r = blockIdx.x * blockDim.x + threadIdx.x;
    if (r >= RR) return;
    float cum = 0.f;
    double im0 = 0, im1 = 0, im2 = 0, dep = 0, aw = 0;
    for (int s = 0; s < SS; ++s) {
        float4 v = pt4[r * SS + s];
        float tv = tb[r * SS + s];
        float T = (float)exp(-(double)cum);
        float e = (float)exp(-(double)v.x);
        float wgt = (1.0f - e) * T;
        im0 += (double)(wgt * v.y);
        im1 += (double)(wgt * v.z);
        im2 += (double)(wgt * v.w);
        dep += (double)(wgt * tv);
        aw  += (double)wgt;
        cum += v.x;
    }
    float accf = (float)aw;
    out[r * 3 + 0] = (float)im0 + (1.0f - accf) * bg[0];
    out[r * 3 + 1] = (float)im1 + (1.0f - accf) * bg[1];
    out[r * 3 + 2] = (float)im2 + (1.0f - accf) * bg[2];
    out[RR * 3 + r] = (float)dep;
}

// ============================ launch =========================================
extern "C" void kernel_launch(void* const* d_in, const int* in_sizes, int n_in,
                              void* d_out, int out_size, void* d_ws, size_t ws_size,
                              hipStream_t stream) {
    const int*   n    = (const int*)d_in[0];
    const int*   h    = (const int*)d_in[1];
    const int*   w    = (const int*)d_in[2];
    const float* intr = (const float*)d_in[3];
    const float* extr = (const float*)d_in[4];
    const float* bds  = (const float*)d_in[5];
    const float* tn   = (const float*)d_in[6];
    const float* htab = (const float*)d_in[7];
    const float* sw1  = (const float*)d_in[8];
    const float* sw2  = (const float*)d_in[9];
    const float* rw1  = (const float*)d_in[10];
    const float* rw2  = (const float*)d_in[11];
    const float* rw3  = (const float*)d_in[12];
    const float* grid = (const float*)d_in[13];
    const float* bg   = (const float*)d_in[14];

    char* ws = (char*)d_ws;
    double* part   = (double*)(ws + OFF_PART);
    float*  meanf  = (float*)(ws + OFF_MEAN);
    int*    cnt    = (int*)(ws + OFF_CNT);
    float4* out4   = (float4*)(ws + OFF_OUT4);
    float*  tbuf   = (float*)(ws + OFF_TBUF);
    int*    plist  = (int*)(ws + OFF_PLIST);
    int*    plist2 = (int*)(ws + OFF_PLIST2);
    float*  rayd   = (float*)(ws + OFF_RAYD);
    float*  h1p    = (float*)(ws + OFF_H1P);
    float4* gst4   = (float4*)(ws + OFF_GST);
    float2* feat   = (float2*)(ws + OFF_FEAT);
    float*  out    = (float*)d_out;

    k_mean_part<<<dim3(256), dim3(256), 0, stream>>>(grid, part);
    k_mean_fin<<<dim3(1), dim3(256), 0, stream>>>(part, meanf, cnt);

    if (ws_size >= WS_NEED2) {
        // XCD level-pinned split-encode path
        k_ray_pre<<<dim3(RR / 4), dim3(256), 0, stream>>>(
            n, h, w, intr, extr, bds, rw1, rayd, h1p);
        k_classify<<<dim3(PP / 1024), dim3(1024), 0, stream>>>(
            tn, rayd, grid, meanf, tbuf, out4, plist, cnt);
        k_enc<<<dim3(8, PP / 256), dim3(256), 0, stream>>>(
            tn, rayd, htab, plist, cnt, feat, 0);
        k_enc<<<dim3(8, PP / 256), dim3(256), 0, stream>>>(
            tn, rayd, htab, plist, cnt, feat, 8);
        k_sig<<<dim3(PP / 256), dim3(256), 0, stream>>>(
            tn, rayd, sw1, sw2, plist, cnt, cnt + 1, out4, plist2, gst4, feat);
        k_rgb<<<dim3(PP / 256), dim3(256), 0, stream>>>(
            rw1, rw2, rw3, plist2, cnt + 1, h1p, gst4, out4);
        k_comp<<<dim3(RR / 4), dim3(256), 0, stream>>>(out4, tbuf, bg, out);
    } else if (ws_size >= WS_NEED) {
        // round-6 fused path
        k_ray_pre<<<dim3(RR / 4), dim3(256), 0, stream>>>(
            n, h, w, intr, extr, bds, rw1, rayd, h1p);
        k_sigall<<<dim3(PP / 256), dim3(256), 0, stream>>>(
            tn, rayd, grid, meanf, htab, sw1, sw2, cnt + 1, out4, tbuf, plist2, gst4);
        k_rgb<<<dim3(PP / 256), dim3(256), 0, stream>>>(
            rw1, rw2, rw3, plist2, cnt + 1, h1p, gst4, out4);
        k_comp<<<dim3(RR / 4), dim3(256), 0, stream>>>(out4, tbuf, bg, out);
    } else {
        k_points_fb<<<dim3(PP / 256), dim3(256), 0, stream>>>(
            n, h, w, intr, extr, bds, tn, htab, sw1, sw2, rw1, rw2, rw3,
            grid, meanf, out4, tbuf);
        k_rays_fb<<<dim3((RR + 255) / 256), dim3(256), 0, stream>>>(out4, tbuf, bg, out);
    }
}